// Round 5
// baseline (229.971 us; speedup 1.0000x reference)
//
#include <hip/hip_runtime.h>
#include <hip/hip_bf16.h>
#include <stdint.h>

typedef unsigned short u16;
typedef float f32x4 __attribute__((ext_vector_type(4)));
typedef short s16x8 __attribute__((ext_vector_type(8)));
typedef u16   u16x8 __attribute__((ext_vector_type(8)));
typedef u16   u16x4 __attribute__((ext_vector_type(4)));
typedef uint32_t u32x4 __attribute__((ext_vector_type(4)));

#define B_      4096
#define D_      256
#define NA_     131072
#define NM_     32768
#define N2_     8192
#define THR4    6.2499950e-6f   /* (0.05 - 1e-8)^4 : d2 < THR4 <=> sqrt(sqrt(d2))+1e-8 < 0.05 */
#define K2E     14.426950408889634f  /* 10*log2(e): exp(10a-10) = exp2(a*K2E - K2E) */

// ---- workspace layout (bytes) ----
#define OFF_CNT_G   0u          // 4096 int
#define OFF_CNT_S   16384u      // 4096 int
#define OFF_CUR_G   32768u      // 4096 int
#define OFF_CUR_S   49152u      // 4096 int
#define OFF_NB      65536u      // 4096 int
#define OFF_SCAL    81920u      // f32[0]=llocal f32[1]=lsc int[3]=batch_max
#define ZERO_BYTES  98304u
#define OFF_T       98304u      // 8192 f32 (fully written by k_tfix)
#define OFF_C       131072u     // 8192 int (fully written by k_tfix)
#define OFF_S       163840u     // 8192 f32 (fully written by k_sred)
#define OFF_PLIST   196608u     // 4096*32 int
#define OFF_OFFS_G  720896u
#define OFF_OFFS_S  737280u
// UNION region: sortg/sorts (used through k_segmean) then SP (used from k_gemm on)
#define OFF_SORT_G  753664u     // 131072 int
#define OFF_SORT_S  1277952u    // 32768 int
#define OFF_SP      753664u     // 128*8192 f32 = 4 MB (aliases sort bufs; lifetimes disjoint)
#define OFF_E       4947968u    // 8192*256 bf16 = 4 MB
#define WS_NEED     9142272u

__device__ inline float wave_sum(float v) {
#pragma unroll
  for (int m = 1; m < 64; m <<= 1) v += __shfl_xor(v, m, 64);
  return v;
}
__device__ inline int wave_sum_i(int v) {
#pragma unroll
  for (int m = 1; m < 64; m <<= 1) v += __shfl_xor(v, m, 64);
  return v;
}
__device__ inline u16 f2bf(float f) {
  uint32_t u = __float_as_uint(f);
  uint32_t r = (u + 0x7FFFu + ((u >> 16) & 1u)) >> 16;
  return (u16)r;
}
__device__ inline float bf2f(u16 v) { return __uint_as_float(((uint32_t)v) << 16); }

// ---- zero the counter region (replaces 76us graph memset node) ----
__global__ void k_zero(u32x4* __restrict__ p) {
  u32x4 z = {0u, 0u, 0u, 0u};
  p[blockIdx.x * 256 + threadIdx.x] = z;   // 24 blocks * 256 * 16B = 98304 B
}

// ---- counts + batch max ----
__global__ void k_count(const int* __restrict__ bg, const int* __restrict__ bs,
                        int* cntg, int* cnts, int* bmax) {
  int i = blockIdx.x * 256 + threadIdx.x;
  int b = -1;
  if (i < NA_) { b = bg[i]; atomicAdd(&cntg[b], 1); }
  if (i < NM_) { atomicAdd(&cnts[bs[i]], 1); }
  int m = b;
#pragma unroll
  for (int k = 1; k < 64; k <<= 1) m = max(m, __shfl_xor(m, k, 64));
  if ((threadIdx.x & 63) == 0 && m >= 0) atomicMax(bmax, m);
}

// ---- exclusive scan of 4096 counts (blockIdx 0 = atoms, 1 = motifs) ----
__global__ void k_scan(const int* __restrict__ cntg, const int* __restrict__ cnts,
                       int* offsg, int* offss, int* curg, int* curs) {
  const int* cnt = blockIdx.x == 0 ? cntg : cnts;
  int* offs = blockIdx.x == 0 ? offsg : offss;
  int* cur  = blockIdx.x == 0 ? curg  : curs;
  __shared__ int ls[256];
  int t = threadIdx.x;
  int v[16]; int s = 0;
#pragma unroll
  for (int k = 0; k < 16; k++) { v[k] = cnt[t * 16 + k]; s += v[k]; }
  ls[t] = s;
  __syncthreads();
  for (int off = 1; off < 256; off <<= 1) {
    int add = (t >= off) ? ls[t - off] : 0;
    __syncthreads();
    ls[t] += add;
    __syncthreads();
  }
  int pre = t ? ls[t - 1] : 0;
#pragma unroll
  for (int k = 0; k < 16; k++) { offs[t * 16 + k] = pre; cur[t * 16 + k] = pre; pre += v[k]; }
}

// ---- scatter into sorted order ----
__global__ void k_scatter(const int* __restrict__ bg, const int* __restrict__ bs,
                          int* curg, int* curs, int* sortg, int* sorts) {
  int i = blockIdx.x * 256 + threadIdx.x;
  if (i < NA_) { int b = bg[i]; sortg[atomicAdd(&curg[b], 1)] = i; }
  if (i < NM_) { int b = bs[i]; sorts[atomicAdd(&curs[b], 1)] = i; }
}

// ---- wave-autonomous segmented mean gather: one wave per batch row, NO barriers ----
__device__ inline void wave_row_sum(const float* __restrict__ src,
                                    const int* __restrict__ sorted,
                                    int off, int cnt, int lane, f32x4* accs) {
  f32x4 a0 = {0.f,0.f,0.f,0.f}, a1 = a0, a2 = a0, a3 = a0;
  f32x4 a4 = a0, a5 = a0, a6 = a0, a7 = a0;
  for (int base = 0; base < cnt; base += 64) {
    int n = min(cnt - base, 64);
    int idx = (lane < n) ? sorted[off + base + lane] : 0;
    int k = 0;
    for (; k + 7 < n; k += 8) {
      int i0 = __shfl(idx, k,     64), i1 = __shfl(idx, k + 1, 64);
      int i2 = __shfl(idx, k + 2, 64), i3 = __shfl(idx, k + 3, 64);
      int i4 = __shfl(idx, k + 4, 64), i5 = __shfl(idx, k + 5, 64);
      int i6 = __shfl(idx, k + 6, 64), i7 = __shfl(idx, k + 7, 64);
      a0 += *(const f32x4*)(src + (size_t)i0 * D_ + lane * 4);
      a1 += *(const f32x4*)(src + (size_t)i1 * D_ + lane * 4);
      a2 += *(const f32x4*)(src + (size_t)i2 * D_ + lane * 4);
      a3 += *(const f32x4*)(src + (size_t)i3 * D_ + lane * 4);
      a4 += *(const f32x4*)(src + (size_t)i4 * D_ + lane * 4);
      a5 += *(const f32x4*)(src + (size_t)i5 * D_ + lane * 4);
      a6 += *(const f32x4*)(src + (size_t)i6 * D_ + lane * 4);
      a7 += *(const f32x4*)(src + (size_t)i7 * D_ + lane * 4);
    }
    for (; k < n; k++) {
      int i0 = __shfl(idx, k, 64);
      a0 += *(const f32x4*)(src + (size_t)i0 * D_ + lane * 4);
    }
  }
  *accs = ((a0 + a1) + (a2 + a3)) + ((a4 + a5) + (a6 + a7));
}

__global__ __launch_bounds__(256) void k_segmean(
    const float* __restrict__ fg, const float* __restrict__ fm,
    const int* __restrict__ cntg, const int* __restrict__ cnts,
    const int* __restrict__ offsg, const int* __restrict__ offss,
    const int* __restrict__ sortg, const int* __restrict__ sorts,
    float* __restrict__ scal) {
  int t = threadIdx.x, w = t >> 6, lane = t & 63;
  int b = blockIdx.x * 4 + w;
  int cg = cntg[b], cs = cnts[b];
  int og = offsg[b], os = offss[b];

  f32x4 sg, ss;
  wave_row_sum(fg, sortg, og, cg, lane, &sg);
  wave_row_sum(fm, sorts, os, cs, lane, &ss);

  float ig = 1.f / fmaxf((float)cg, 1.f);
  float is = 1.f / fmaxf((float)cs, 1.f);
  float dx = sg.x * ig - ss.x * is, dy = sg.y * ig - ss.y * is;
  float dz = sg.z * ig - ss.z * is, dw = sg.w * ig - ss.w * is;
  float v = wave_sum(dx * dx + dy * dy + dz * dz + dw * dw);

  __shared__ float r2[4];
  if (lane == 0) r2[w] = (cg > 0 && cs > 0) ? sqrtf(v) : 0.f;
  __syncthreads();
  if (t == 0) {
    float s = r2[0] + r2[1] + r2[2] + r2[3];
    if (s != 0.f) atomicAdd(&scal[0], s);
  }
}

// ---- sparse prop-neighbor lists over the 4096 base rows ----
__global__ void k_pairs(const float* __restrict__ pp, int* __restrict__ nb,
                        int* __restrict__ plist) {
  int a = blockIdx.x;
  f32x4 pa = *(const f32x4*)(pp + (size_t)a * 4);
  for (int b = threadIdx.x; b < B_; b += 256) {
    f32x4 pb = *(const f32x4*)(pp + (size_t)b * 4);
    float dx = pa.x - pb.x, dy = pa.y - pb.y, dz = pa.z - pb.z, dw = pa.w - pb.w;
    float d2 = dx * dx + dy * dy + dz * dz + dw * dw;
    if (d2 < THR4) {
      int pos = atomicAdd(&nb[a], 1);
      if (pos < 32) plist[a * 32 + pos] = b;
    }
  }
}

// ---- normalize combined embeddings -> bf16 ----
__global__ void k_norm(const float* __restrict__ gm, const float* __restrict__ scm,
                       u16* __restrict__ E) {
  int w = threadIdx.x >> 6, lane = threadIdx.x & 63;
  int r = blockIdx.x * 4 + w;
  const float* src = (r < B_) ? gm + (size_t)r * D_ : scm + (size_t)(r - B_) * D_;
  f32x4 v = *(const f32x4*)(src + lane * 4);
  float ss = v.x * v.x + v.y * v.y + v.z * v.z + v.w * v.w;
  ss = wave_sum(ss);
  float inv = 1.f / fmaxf(sqrtf(ss), 1e-12f);
  u16x4 o;
  o.x = f2bf(v.x * inv); o.y = f2bf(v.y * inv);
  o.z = f2bf(v.z * inv); o.w = f2bf(v.w * inv);
  *(u16x4*)(E + (size_t)r * D_ + lane * 4) = o;
}

// ---- fused Gram + row-sum-of-exp, upper-triangular tiles with symmetric col-sums ----
// 2080 blocks = triangular (bi<=bj) over 64x64 tile grid of 128x128 tiles.
__global__ __launch_bounds__(256) void k_gemm(const u16* __restrict__ E,
                                              float* __restrict__ SP) {
  __shared__ __align__(16) u16 As[128 * 64];
  __shared__ __align__(16) u16 Bs[128 * 64];

  // triangular decode: P(bi) = bi*(129-bi)/2
  int t = blockIdx.x;
  int bi = (int)((129.0f - sqrtf(129.0f * 129.0f - 8.0f * (float)t)) * 0.5f);
  while ((bi + 1) * (129 - (bi + 1)) / 2 <= t) bi++;
  while (bi * (129 - bi) / 2 > t) bi--;
  int bj = bi + (t - bi * (129 - bi) / 2);

  int row0 = bi * 128, col0 = bj * 128;
  int tid = threadIdx.x, lane = tid & 63, wid = tid >> 6;
  int wr = wid >> 1, wc = wid & 1;

  f32x4 acc[4][4];
#pragma unroll
  for (int mi = 0; mi < 4; mi++)
#pragma unroll
    for (int ni = 0; ni < 4; ni++) {
      f32x4 z = {0.f, 0.f, 0.f, 0.f};
      acc[mi][ni] = z;
    }

  for (int kc = 0; kc < 4; ++kc) {
    __syncthreads();
#pragma unroll
    for (int p = 0; p < 4; p++) {
      int idx = p * 256 + tid;          // 0..1023
      int r = idx >> 3;
      int c16 = idx & 7;
      int cb = c16 * 16;                 // dest byte col (linear)
      int cbs = cb ^ ((r & 7) << 4);     // source byte col (pre-swizzled)
      u16x8 va = *(const u16x8*)(E + (size_t)(row0 + r) * D_ + kc * 64 + (cbs >> 1));
      *(u16x8*)(As + r * 64 + c16 * 8) = va;
      u16x8 vb = *(const u16x8*)(E + (size_t)(col0 + r) * D_ + kc * 64 + (cbs >> 1));
      *(u16x8*)(Bs + r * 64 + c16 * 8) = vb;
    }
    __syncthreads();
#pragma unroll
    for (int kk = 0; kk < 2; ++kk) {
      s16x8 af[4], bfr[4];
#pragma unroll
      for (int mi = 0; mi < 4; mi++) {
        int rA = wr * 64 + mi * 16 + (lane & 15);
        int cbf = kk * 64 + (lane >> 4) * 16;
        int addr = rA * 128 + (cbf ^ ((rA & 7) << 4));
        af[mi] = *(const s16x8*)((const char*)As + addr);
      }
#pragma unroll
      for (int ni = 0; ni < 4; ni++) {
        int rB = wc * 64 + ni * 16 + (lane & 15);
        int cbf = kk * 64 + (lane >> 4) * 16;
        int addr = rB * 128 + (cbf ^ ((rB & 7) << 4));
        bfr[ni] = *(const s16x8*)((const char*)Bs + addr);
      }
#pragma unroll
      for (int mi = 0; mi < 4; mi++)
#pragma unroll
        for (int ni = 0; ni < 4; ni++)
          acc[mi][ni] = __builtin_amdgcn_mfma_f32_16x16x32_bf16(af[mi], bfr[ni], acc[mi][ni], 0, 0, 0);
    }
  }

  // epilogue: exp(10a-10) = exp2(a*K2E - K2E); row sums + (off-diag) col sums
  int g = lane >> 4, cl = lane & 15;
  int sliceR = bj * 2 + wc;
  float colsum[4] = {0.f, 0.f, 0.f, 0.f};
#pragma unroll
  for (int mi = 0; mi < 4; mi++) {
#pragma unroll
    for (int reg = 0; reg < 4; ++reg) {
      int gi = row0 + wr * 64 + mi * 16 + g * 4 + reg;
      float vs = 0.f;
#pragma unroll
      for (int ni = 0; ni < 4; ni++) {
        float e = exp2f(acc[mi][ni][reg] * K2E - K2E);
        vs += e;
        colsum[ni] += e;
      }
#pragma unroll
      for (int m = 1; m < 16; m <<= 1) vs += __shfl_xor(vs, m, 64);
      if (cl == 0) SP[(size_t)sliceR * N2_ + gi] = vs;
    }
  }
  if (bi != bj) {
    int sliceC = bi * 2 + wr;
#pragma unroll
    for (int ni = 0; ni < 4; ni++) {
      float cs = colsum[ni];
      cs += __shfl_xor(cs, 16, 64);
      cs += __shfl_xor(cs, 32, 64);
      if (g == 0) SP[(size_t)sliceC * N2_ + col0 + wc * 64 + ni * 16 + cl] = cs;
    }
  }
}

// ---- reduce S partials: S[gi] = sum over 128 slices ----
__global__ void k_sred(const float* __restrict__ SP, float* __restrict__ S) {
  int gi = blockIdx.x * 256 + threadIdx.x;
  float s = 0.f;
  for (int k = 0; k < 128; k++) s += SP[(size_t)k * N2_ + gi];
  S[gi] = s;
}

// ---- T[i] = 10*(sum_{b in list(a)} [dot(e_i,e_b)+dot(e_i,e_{b+B})] - dot(e_i,e_i)); C[i]=2n-1 ----
__global__ void k_tfix(const u16* __restrict__ E, const int* __restrict__ nb,
                       const int* __restrict__ plist, float* __restrict__ T,
                       int* __restrict__ C) {
  int w = threadIdx.x >> 6, lane = threadIdx.x & 63;
  int i = blockIdx.x * 4 + w;
  int a = i & (B_ - 1);
  int n = min(nb[a], 32);
  u16x4 vi = *(const u16x4*)(E + (size_t)i * D_ + lane * 4);
  float ex = bf2f(vi.x), ey = bf2f(vi.y), ez = bf2f(vi.z), ew = bf2f(vi.w);
  float acc = -(ex * ex + ey * ey + ez * ez + ew * ew);   // subtract self-dot
  for (int k = 0; k < n; k++) {
    int b = plist[a * 32 + k];
    u16x4 v1 = *(const u16x4*)(E + (size_t)b * D_ + lane * 4);
    u16x4 v2 = *(const u16x4*)(E + (size_t)(b + B_) * D_ + lane * 4);
    acc += ex * bf2f(v1.x) + ey * bf2f(v1.y) + ez * bf2f(v1.z) + ew * bf2f(v1.w);
    acc += ex * bf2f(v2.x) + ey * bf2f(v2.y) + ez * bf2f(v2.z) + ew * bf2f(v2.w);
  }
  acc = wave_sum(acc);
  if (lane == 0) { T[i] = 10.0f * acc; C[i] = 2 * n - 1; }
}

// ---- l_sc_g: mean row norm of (emb_sc_shape - emb_shape) ----
__global__ void k_lsc(const float* __restrict__ a, const float* __restrict__ b,
                      float* __restrict__ scal) {
  int w = threadIdx.x >> 6, lane = threadIdx.x & 63;
  int wg = blockIdx.x * 4 + w;
  float acc = 0.f;
  for (int r = wg; r < NM_; r += 8192) {
    f32x4 va = *(const f32x4*)(a + (size_t)r * D_ + lane * 4);
    f32x4 vb = *(const f32x4*)(b + (size_t)r * D_ + lane * 4);
    float dx = va.x - vb.x, dy = va.y - vb.y, dz = va.z - vb.z, dw = va.w - vb.w;
    float ss = wave_sum(dx * dx + dy * dy + dz * dz + dw * dw);
    if (lane == 0) acc += sqrtf(ss);
  }
  __shared__ float red[4];
  if (lane == 0) red[w] = acc;
  __syncthreads();
  if (threadIdx.x == 0) atomicAdd(&scal[1], red[0] + red[1] + red[2] + red[3]);
}

// ---- final combine (+ l_prop fused) ----
__global__ void k_final(const float* __restrict__ S, const float* __restrict__ T,
                        const int* __restrict__ C, const float* __restrict__ scal,
                        const float* __restrict__ pp, const float* __restrict__ pt,
                        float* __restrict__ out) {
  float sp = 0.f;
  for (int i = threadIdx.x; i < B_ * 4; i += 256) {
    float d = pp[i] - pt[i];
    sp += d * d;
  }
  float rls = 0.f; int nv = 0;
  for (int i = threadIdx.x; i < N2_; i += 256) {
    int ci = C[i];
    if (ci > 0) { rls += (10.0f + logf(S[i])) - T[i] / (float)ci; nv++; }
  }
  rls = wave_sum(rls);
  sp  = wave_sum(sp);
  nv  = wave_sum_i(nv);
  __shared__ float r1[4], r3[4]; __shared__ int r2[4];
  int lane = threadIdx.x & 63, w = threadIdx.x >> 6;
  if (lane == 0) { r1[w] = rls; r2[w] = nv; r3[w] = sp; }
  __syncthreads();
  if (threadIdx.x == 0) {
    float rtot = r1[0] + r1[1] + r1[2] + r1[3];
    int nvt = r2[0] + r2[1] + r2[2] + r2[3];
    float sptot = r3[0] + r3[1] + r3[2] + r3[3];
    float l_contr = nvt > 0 ? rtot / (float)nvt : 0.f;
    int bmax = ((const int*)scal)[3];
    float bs = (float)bmax + 1.0f;
    float l_local_g = scal[0] / bs;
    float l_sc = scal[1] / (float)NM_;
    float l_prop = sptot / (float)(B_ * 4);
    float l_hes = 1.0f * l_local_g + 0.8f * l_contr + 1.0f * l_sc + 0.8f * l_contr + 0.5f * l_prop;
    out[0] = l_hes; out[1] = l_local_g; out[2] = l_contr;
    out[3] = l_sc;  out[4] = l_contr;   out[5] = l_prop;
  }
}

extern "C" void kernel_launch(void* const* d_in, const int* in_sizes, int n_in,
                              void* d_out, int out_size, void* d_ws, size_t ws_size,
                              hipStream_t stream) {
  if (ws_size < WS_NEED) return;
  const float* gm  = (const float*)d_in[0];
  const float* fg  = (const float*)d_in[1];
  const float* scm = (const float*)d_in[2];
  const float* scs = (const float*)d_in[3];
  const float* mot = (const float*)d_in[4];
  const float* shp = (const float*)d_in[5];
  const float* pp  = (const float*)d_in[6];
  const float* pt  = (const float*)d_in[7];
  const int* bg = (const int*)d_in[8];
  const int* bs = (const int*)d_in[9];
  float* out = (float*)d_out;
  char* ws = (char*)d_ws;

  int* cntg  = (int*)(ws + OFF_CNT_G);
  int* cnts  = (int*)(ws + OFF_CNT_S);
  int* curg  = (int*)(ws + OFF_CUR_G);
  int* curs  = (int*)(ws + OFF_CUR_S);
  int* nb    = (int*)(ws + OFF_NB);
  float* scal = (float*)(ws + OFF_SCAL);
  float* T   = (float*)(ws + OFF_T);
  int* C     = (int*)(ws + OFF_C);
  float* S   = (float*)(ws + OFF_S);
  int* plist = (int*)(ws + OFF_PLIST);
  int* offsg = (int*)(ws + OFF_OFFS_G);
  int* offss = (int*)(ws + OFF_OFFS_S);
  int* sortg = (int*)(ws + OFF_SORT_G);
  int* sorts = (int*)(ws + OFF_SORT_S);
  float* SP  = (float*)(ws + OFF_SP);
  u16* E     = (u16*)(ws + OFF_E);

  k_zero<<<24, 256, 0, stream>>>((u32x4*)ws);   // zeroes [0, ZERO_BYTES)
  k_count<<<512, 256, 0, stream>>>(bg, bs, cntg, cnts, (int*)scal + 3);
  k_scan<<<2, 256, 0, stream>>>(cntg, cnts, offsg, offss, curg, curs);
  k_scatter<<<512, 256, 0, stream>>>(bg, bs, curg, curs, sortg, sorts);
  k_segmean<<<1024, 256, 0, stream>>>(fg, mot, cntg, cnts, offsg, offss, sortg, sorts, scal);
  k_pairs<<<4096, 256, 0, stream>>>(pp, nb, plist);
  k_norm<<<2048, 256, 0, stream>>>(gm, scm, E);
  k_gemm<<<2080, 256, 0, stream>>>(E, SP);     // SP aliases sort bufs; segmean already done
  k_sred<<<32, 256, 0, stream>>>(SP, S);
  k_tfix<<<2048, 256, 0, stream>>>(E, nb, plist, T, C);
  k_lsc<<<2048, 256, 0, stream>>>(scs, shp, scal);
  k_final<<<1, 256, 0, stream>>>(S, T, C, scal, pp, pt, out);
}

// Round 6
// 215.407 us; speedup vs baseline: 1.0676x; 1.0676x over previous
//
#include <hip/hip_runtime.h>
#include <hip/hip_bf16.h>
#include <stdint.h>

typedef unsigned short u16;
typedef float f32x4 __attribute__((ext_vector_type(4)));
typedef short s16x8 __attribute__((ext_vector_type(8)));
typedef u16   u16x8 __attribute__((ext_vector_type(8)));
typedef u16   u16x4 __attribute__((ext_vector_type(4)));
typedef uint32_t u32x4 __attribute__((ext_vector_type(4)));

#define B_      4096
#define D_      256
#define NA_     131072
#define NM_     32768
#define N2_     8192
#define THR4    6.2499950e-6f   /* (0.05 - 1e-8)^4 */
#define K2E     14.426950408889634f  /* 10*log2(e) */

// ---- workspace layout (bytes) ----
#define OFF_CNT_G   0u
#define OFF_CNT_S   16384u
#define OFF_CUR_G   32768u
#define OFF_CUR_S   49152u
#define OFF_NB      65536u
#define OFF_SCAL    81920u
#define ZERO_BYTES  98304u
#define OFF_T       98304u
#define OFF_C       131072u
#define OFF_S       163840u
#define OFF_PLIST   196608u
#define OFF_OFFS_G  720896u
#define OFF_OFFS_S  737280u
#define OFF_SORT_G  753664u
#define OFF_SORT_S  1277952u
#define OFF_SP      753664u     // aliases sort bufs; lifetimes disjoint
#define OFF_E       4947968u
#define WS_NEED     9142272u

__device__ inline float wave_sum(float v) {
#pragma unroll
  for (int m = 1; m < 64; m <<= 1) v += __shfl_xor(v, m, 64);
  return v;
}
__device__ inline int wave_sum_i(int v) {
#pragma unroll
  for (int m = 1; m < 64; m <<= 1) v += __shfl_xor(v, m, 64);
  return v;
}
__device__ inline u16 f2bf(float f) {
  uint32_t u = __float_as_uint(f);
  uint32_t r = (u + 0x7FFFu + ((u >> 16) & 1u)) >> 16;
  return (u16)r;
}
__device__ inline float bf2f(u16 v) { return __uint_as_float(((uint32_t)v) << 16); }

// async global->LDS, 16B per lane; dst is wave-uniform base, HW adds lane*16
__device__ inline void gload16(const u16* __restrict__ g, u16* l) {
  __builtin_amdgcn_global_load_lds(
      (const __attribute__((address_space(1))) uint32_t*)g,
      (__attribute__((address_space(3))) uint32_t*)l, 16, 0, 0);
}

// ---- zero the counter region ----
__global__ void k_zero(u32x4* __restrict__ p) {
  u32x4 z = {0u, 0u, 0u, 0u};
  p[blockIdx.x * 256 + threadIdx.x] = z;   // 24*256*16B = 98304 B
}

// ---- counts + batch max ----
__global__ void k_count(const int* __restrict__ bg, const int* __restrict__ bs,
                        int* cntg, int* cnts, int* bmax) {
  int i = blockIdx.x * 256 + threadIdx.x;
  int b = -1;
  if (i < NA_) { b = bg[i]; atomicAdd(&cntg[b], 1); }
  if (i < NM_) { atomicAdd(&cnts[bs[i]], 1); }
  int m = b;
#pragma unroll
  for (int k = 1; k < 64; k <<= 1) m = max(m, __shfl_xor(m, k, 64));
  if ((threadIdx.x & 63) == 0 && m >= 0) atomicMax(bmax, m);
}

// ---- exclusive scan of 4096 counts ----
__global__ void k_scan(const int* __restrict__ cntg, const int* __restrict__ cnts,
                       int* offsg, int* offss, int* curg, int* curs) {
  const int* cnt = blockIdx.x == 0 ? cntg : cnts;
  int* offs = blockIdx.x == 0 ? offsg : offss;
  int* cur  = blockIdx.x == 0 ? curg  : curs;
  __shared__ int ls[256];
  int t = threadIdx.x;
  int v[16]; int s = 0;
#pragma unroll
  for (int k = 0; k < 16; k++) { v[k] = cnt[t * 16 + k]; s += v[k]; }
  ls[t] = s;
  __syncthreads();
  for (int off = 1; off < 256; off <<= 1) {
    int add = (t >= off) ? ls[t - off] : 0;
    __syncthreads();
    ls[t] += add;
    __syncthreads();
  }
  int pre = t ? ls[t - 1] : 0;
#pragma unroll
  for (int k = 0; k < 16; k++) { offs[t * 16 + k] = pre; cur[t * 16 + k] = pre; pre += v[k]; }
}

// ---- scatter into sorted order ----
__global__ void k_scatter(const int* __restrict__ bg, const int* __restrict__ bs,
                          int* curg, int* curs, int* sortg, int* sorts) {
  int i = blockIdx.x * 256 + threadIdx.x;
  if (i < NA_) { int b = bg[i]; sortg[atomicAdd(&curg[b], 1)] = i; }
  if (i < NM_) { int b = bs[i]; sorts[atomicAdd(&curs[b], 1)] = i; }
}

// ---- wave-autonomous segmented mean gather ----
__device__ inline void wave_row_sum(const float* __restrict__ src,
                                    const int* __restrict__ sorted,
                                    int off, int cnt, int lane, f32x4* accs) {
  f32x4 a0 = {0.f,0.f,0.f,0.f}, a1 = a0, a2 = a0, a3 = a0;
  f32x4 a4 = a0, a5 = a0, a6 = a0, a7 = a0;
  for (int base = 0; base < cnt; base += 64) {
    int n = min(cnt - base, 64);
    int idx = (lane < n) ? sorted[off + base + lane] : 0;
    int k = 0;
    for (; k + 7 < n; k += 8) {
      int i0 = __shfl(idx, k,     64), i1 = __shfl(idx, k + 1, 64);
      int i2 = __shfl(idx, k + 2, 64), i3 = __shfl(idx, k + 3, 64);
      int i4 = __shfl(idx, k + 4, 64), i5 = __shfl(idx, k + 5, 64);
      int i6 = __shfl(idx, k + 6, 64), i7 = __shfl(idx, k + 7, 64);
      a0 += *(const f32x4*)(src + (size_t)i0 * D_ + lane * 4);
      a1 += *(const f32x4*)(src + (size_t)i1 * D_ + lane * 4);
      a2 += *(const f32x4*)(src + (size_t)i2 * D_ + lane * 4);
      a3 += *(const f32x4*)(src + (size_t)i3 * D_ + lane * 4);
      a4 += *(const f32x4*)(src + (size_t)i4 * D_ + lane * 4);
      a5 += *(const f32x4*)(src + (size_t)i5 * D_ + lane * 4);
      a6 += *(const f32x4*)(src + (size_t)i6 * D_ + lane * 4);
      a7 += *(const f32x4*)(src + (size_t)i7 * D_ + lane * 4);
    }
    for (; k < n; k++) {
      int i0 = __shfl(idx, k, 64);
      a0 += *(const f32x4*)(src + (size_t)i0 * D_ + lane * 4);
    }
  }
  *accs = ((a0 + a1) + (a2 + a3)) + ((a4 + a5) + (a6 + a7));
}

// ---- fused: segmean [0,1024) | lsc [1024,3072) | norm [3072,5120) | pairs [5120,9216) ----
__global__ __launch_bounds__(256) void k_fuse1(
    const float* __restrict__ fg, const float* __restrict__ fm,
    const int* __restrict__ cntg, const int* __restrict__ cnts,
    const int* __restrict__ offsg, const int* __restrict__ offss,
    const int* __restrict__ sortg, const int* __restrict__ sorts,
    const float* __restrict__ scs, const float* __restrict__ shp,
    const float* __restrict__ gm, const float* __restrict__ scm,
    const float* __restrict__ pp,
    u16* __restrict__ E, int* __restrict__ nb, int* __restrict__ plist,
    float* __restrict__ scal) {
  int t = threadIdx.x, w = t >> 6, lane = t & 63;
  int blk = blockIdx.x;
  __shared__ float sr4[4];

  if (blk < 1024) {               // ---- segmean ----
    int b = blk * 4 + w;
    int cg = cntg[b], cs = cnts[b];
    int og = offsg[b], os = offss[b];
    f32x4 sg, ss;
    wave_row_sum(fg, sortg, og, cg, lane, &sg);
    wave_row_sum(fm, sorts, os, cs, lane, &ss);
    float ig = 1.f / fmaxf((float)cg, 1.f);
    float is = 1.f / fmaxf((float)cs, 1.f);
    float dx = sg.x * ig - ss.x * is, dy = sg.y * ig - ss.y * is;
    float dz = sg.z * ig - ss.z * is, dw = sg.w * ig - ss.w * is;
    float v = wave_sum(dx * dx + dy * dy + dz * dz + dw * dw);
    if (lane == 0) sr4[w] = (cg > 0 && cs > 0) ? sqrtf(v) : 0.f;
    __syncthreads();
    if (t == 0) {
      float s = sr4[0] + sr4[1] + sr4[2] + sr4[3];
      if (s != 0.f) atomicAdd(&scal[0], s);
    }
  } else if (blk < 3072) {        // ---- lsc ----
    int wg = (blk - 1024) * 4 + w;
    float acc = 0.f;
    for (int r = wg; r < NM_; r += 8192) {
      f32x4 va = *(const f32x4*)(scs + (size_t)r * D_ + lane * 4);
      f32x4 vb = *(const f32x4*)(shp + (size_t)r * D_ + lane * 4);
      float dx = va.x - vb.x, dy = va.y - vb.y, dz = va.z - vb.z, dw = va.w - vb.w;
      float ss = wave_sum(dx * dx + dy * dy + dz * dz + dw * dw);
      if (lane == 0) acc += sqrtf(ss);
    }
    if (lane == 0) sr4[w] = acc;
    __syncthreads();
    if (t == 0) atomicAdd(&scal[1], sr4[0] + sr4[1] + sr4[2] + sr4[3]);
  } else if (blk < 5120) {        // ---- norm -> E bf16 ----
    int r = (blk - 3072) * 4 + w;
    const float* src = (r < B_) ? gm + (size_t)r * D_ : scm + (size_t)(r - B_) * D_;
    f32x4 v = *(const f32x4*)(src + lane * 4);
    float ss = v.x * v.x + v.y * v.y + v.z * v.z + v.w * v.w;
    ss = wave_sum(ss);
    float inv = 1.f / fmaxf(sqrtf(ss), 1e-12f);
    u16x4 o;
    o.x = f2bf(v.x * inv); o.y = f2bf(v.y * inv);
    o.z = f2bf(v.z * inv); o.w = f2bf(v.w * inv);
    *(u16x4*)(E + (size_t)r * D_ + lane * 4) = o;
  } else {                        // ---- pairs ----
    int a = blk - 5120;
    f32x4 pa = *(const f32x4*)(pp + (size_t)a * 4);
    for (int b = t; b < B_; b += 256) {
      f32x4 pb = *(const f32x4*)(pp + (size_t)b * 4);
      float dx = pa.x - pb.x, dy = pa.y - pb.y, dz = pa.z - pb.z, dw = pa.w - pb.w;
      float d2 = dx * dx + dy * dy + dz * dz + dw * dw;
      if (d2 < THR4) {
        int pos = atomicAdd(&nb[a], 1);
        if (pos < 32) plist[a * 32 + pos] = b;
      }
    }
  }
}

// ---- fused Gram + row-sum-of-exp, triangular tiles, global_load_lds staging ----
__global__ __launch_bounds__(256) void k_gemm(const u16* __restrict__ E,
                                              float* __restrict__ SP) {
  __shared__ __align__(16) u16 As[128 * 64];
  __shared__ __align__(16) u16 Bs[128 * 64];

  // triangular decode: P(bi) = bi*(129-bi)/2
  int t = blockIdx.x;
  int bi = (int)((129.0f - sqrtf(129.0f * 129.0f - 8.0f * (float)t)) * 0.5f);
  while ((bi + 1) * (129 - (bi + 1)) / 2 <= t) bi++;
  while (bi * (129 - bi) / 2 > t) bi--;
  int bj = bi + (t - bi * (129 - bi) / 2);

  int row0 = bi * 128, col0 = bj * 128;
  int tid = threadIdx.x, lane = tid & 63, wid = tid >> 6;
  int wr = wid >> 1, wc = wid & 1;

  // per-lane source swizzle for gload16: seg s covers bytes [s*1024, s*1024+1024)
  // r = s*8 + (lane>>3), cb = (lane&7)*16, swz col = cb ^ ((r&7)<<4)
  int rsub = lane >> 3;                        // 0..7 within segment
  int csw  = (((lane & 7) ^ rsub) << 4) >> 1;  // swizzled col in u16 elements

  f32x4 acc[4][4];
#pragma unroll
  for (int mi = 0; mi < 4; mi++)
#pragma unroll
    for (int ni = 0; ni < 4; ni++) {
      f32x4 z = {0.f, 0.f, 0.f, 0.f};
      acc[mi][ni] = z;
    }

  for (int kc = 0; kc < 4; ++kc) {
    __syncthreads();   // prev compute's ds_reads done before overwrite
#pragma unroll
    for (int it = 0; it < 4; it++) {
      int s = wid * 4 + it;                    // segment 0..15
      int r = s * 8 + rsub;                    // tile row
      gload16(E + (size_t)(row0 + r) * D_ + kc * 64 + csw, As + s * 512);
      gload16(E + (size_t)(col0 + r) * D_ + kc * 64 + csw, Bs + s * 512);
    }
    __syncthreads();   // drains vmcnt(0): staged data visible
#pragma unroll
    for (int kk = 0; kk < 2; ++kk) {
      s16x8 af[4], bfr[4];
#pragma unroll
      for (int mi = 0; mi < 4; mi++) {
        int rA = wr * 64 + mi * 16 + (lane & 15);
        int cbf = kk * 64 + (lane >> 4) * 16;
        int addr = rA * 128 + (cbf ^ ((rA & 7) << 4));
        af[mi] = *(const s16x8*)((const char*)As + addr);
      }
#pragma unroll
      for (int ni = 0; ni < 4; ni++) {
        int rB = wc * 64 + ni * 16 + (lane & 15);
        int cbf = kk * 64 + (lane >> 4) * 16;
        int addr = rB * 128 + (cbf ^ ((rB & 7) << 4));
        bfr[ni] = *(const s16x8*)((const char*)Bs + addr);
      }
#pragma unroll
      for (int mi = 0; mi < 4; mi++)
#pragma unroll
        for (int ni = 0; ni < 4; ni++)
          acc[mi][ni] = __builtin_amdgcn_mfma_f32_16x16x32_bf16(af[mi], bfr[ni], acc[mi][ni], 0, 0, 0);
    }
  }

  // epilogue: exp(10a-10) = exp2(a*K2E - K2E); row sums + (off-diag) col sums
  int g = lane >> 4, cl = lane & 15;
  int sliceR = bj * 2 + wc;
  float colsum[4] = {0.f, 0.f, 0.f, 0.f};
#pragma unroll
  for (int mi = 0; mi < 4; mi++) {
#pragma unroll
    for (int reg = 0; reg < 4; ++reg) {
      int gi = row0 + wr * 64 + mi * 16 + g * 4 + reg;
      float vs = 0.f;
#pragma unroll
      for (int ni = 0; ni < 4; ni++) {
        float e = exp2f(acc[mi][ni][reg] * K2E - K2E);
        vs += e;
        colsum[ni] += e;
      }
#pragma unroll
      for (int m = 1; m < 16; m <<= 1) vs += __shfl_xor(vs, m, 64);
      if (cl == 0) SP[(size_t)sliceR * N2_ + gi] = vs;
    }
  }
  if (bi != bj) {
    int sliceC = bi * 2 + wr;
#pragma unroll
    for (int ni = 0; ni < 4; ni++) {
      float cs = colsum[ni];
      cs += __shfl_xor(cs, 16, 64);
      cs += __shfl_xor(cs, 32, 64);
      if (g == 0) SP[(size_t)sliceC * N2_ + col0 + wc * 64 + ni * 16 + cl] = cs;
    }
  }
}

// ---- fused: sred [0,32) | tfix [32,2080) ----
__global__ __launch_bounds__(256) void k_fuse2(
    const float* __restrict__ SP, float* __restrict__ S,
    const u16* __restrict__ E, const int* __restrict__ nb,
    const int* __restrict__ plist, float* __restrict__ T, int* __restrict__ C) {
  int blk = blockIdx.x;
  if (blk < 32) {                 // ---- sred ----
    int gi = blk * 256 + threadIdx.x;
    float s = 0.f;
    for (int k = 0; k < 128; k++) s += SP[(size_t)k * N2_ + gi];
    S[gi] = s;
  } else {                        // ---- tfix ----
    int w = threadIdx.x >> 6, lane = threadIdx.x & 63;
    int i = (blk - 32) * 4 + w;
    int a = i & (B_ - 1);
    int n = min(nb[a], 32);
    u16x4 vi = *(const u16x4*)(E + (size_t)i * D_ + lane * 4);
    float ex = bf2f(vi.x), ey = bf2f(vi.y), ez = bf2f(vi.z), ew = bf2f(vi.w);
    float acc = -(ex * ex + ey * ey + ez * ez + ew * ew);
    for (int k = 0; k < n; k++) {
      int b = plist[a * 32 + k];
      u16x4 v1 = *(const u16x4*)(E + (size_t)b * D_ + lane * 4);
      u16x4 v2 = *(const u16x4*)(E + (size_t)(b + B_) * D_ + lane * 4);
      acc += ex * bf2f(v1.x) + ey * bf2f(v1.y) + ez * bf2f(v1.z) + ew * bf2f(v1.w);
      acc += ex * bf2f(v2.x) + ey * bf2f(v2.y) + ez * bf2f(v2.z) + ew * bf2f(v2.w);
    }
    acc = wave_sum(acc);
    if (lane == 0) { T[i] = 10.0f * acc; C[i] = 2 * n - 1; }
  }
}

// ---- final combine (+ l_prop fused) ----
__global__ void k_final(const float* __restrict__ S, const float* __restrict__ T,
                        const int* __restrict__ C, const float* __restrict__ scal,
                        const float* __restrict__ pp, const float* __restrict__ pt,
                        float* __restrict__ out) {
  float sp = 0.f;
  for (int i = threadIdx.x; i < B_ * 4; i += 256) {
    float d = pp[i] - pt[i];
    sp += d * d;
  }
  float rls = 0.f; int nv = 0;
  for (int i = threadIdx.x; i < N2_; i += 256) {
    int ci = C[i];
    if (ci > 0) { rls += (10.0f + logf(S[i])) - T[i] / (float)ci; nv++; }
  }
  rls = wave_sum(rls);
  sp  = wave_sum(sp);
  nv  = wave_sum_i(nv);
  __shared__ float r1[4], r3[4]; __shared__ int r2[4];
  int lane = threadIdx.x & 63, w = threadIdx.x >> 6;
  if (lane == 0) { r1[w] = rls; r2[w] = nv; r3[w] = sp; }
  __syncthreads();
  if (threadIdx.x == 0) {
    float rtot = r1[0] + r1[1] + r1[2] + r1[3];
    int nvt = r2[0] + r2[1] + r2[2] + r2[3];
    float sptot = r3[0] + r3[1] + r3[2] + r3[3];
    float l_contr = nvt > 0 ? rtot / (float)nvt : 0.f;
    int bmax = ((const int*)scal)[3];
    float bs = (float)bmax + 1.0f;
    float l_local_g = scal[0] / bs;
    float l_sc = scal[1] / (float)NM_;
    float l_prop = sptot / (float)(B_ * 4);
    float l_hes = 1.0f * l_local_g + 0.8f * l_contr + 1.0f * l_sc + 0.8f * l_contr + 0.5f * l_prop;
    out[0] = l_hes; out[1] = l_local_g; out[2] = l_contr;
    out[3] = l_sc;  out[4] = l_contr;   out[5] = l_prop;
  }
}

extern "C" void kernel_launch(void* const* d_in, const int* in_sizes, int n_in,
                              void* d_out, int out_size, void* d_ws, size_t ws_size,
                              hipStream_t stream) {
  if (ws_size < WS_NEED) return;
  const float* gm  = (const float*)d_in[0];
  const float* fg  = (const float*)d_in[1];
  const float* scm = (const float*)d_in[2];
  const float* scs = (const float*)d_in[3];
  const float* mot = (const float*)d_in[4];
  const float* shp = (const float*)d_in[5];
  const float* pp  = (const float*)d_in[6];
  const float* pt  = (const float*)d_in[7];
  const int* bg = (const int*)d_in[8];
  const int* bs = (const int*)d_in[9];
  float* out = (float*)d_out;
  char* ws = (char*)d_ws;

  int* cntg  = (int*)(ws + OFF_CNT_G);
  int* cnts  = (int*)(ws + OFF_CNT_S);
  int* curg  = (int*)(ws + OFF_CUR_G);
  int* curs  = (int*)(ws + OFF_CUR_S);
  int* nb    = (int*)(ws + OFF_NB);
  float* scal = (float*)(ws + OFF_SCAL);
  float* T   = (float*)(ws + OFF_T);
  int* C     = (int*)(ws + OFF_C);
  float* S   = (float*)(ws + OFF_S);
  int* plist = (int*)(ws + OFF_PLIST);
  int* offsg = (int*)(ws + OFF_OFFS_G);
  int* offss = (int*)(ws + OFF_OFFS_S);
  int* sortg = (int*)(ws + OFF_SORT_G);
  int* sorts = (int*)(ws + OFF_SORT_S);
  float* SP  = (float*)(ws + OFF_SP);
  u16* E     = (u16*)(ws + OFF_E);

  k_zero<<<24, 256, 0, stream>>>((u32x4*)ws);
  k_count<<<512, 256, 0, stream>>>(bg, bs, cntg, cnts, (int*)scal + 3);
  k_scan<<<2, 256, 0, stream>>>(cntg, cnts, offsg, offss, curg, curs);
  k_scatter<<<512, 256, 0, stream>>>(bg, bs, curg, curs, sortg, sorts);
  k_fuse1<<<9216, 256, 0, stream>>>(fg, mot, cntg, cnts, offsg, offss, sortg, sorts,
                                    scs, shp, gm, scm, pp, E, nb, plist, scal);
  k_gemm<<<2080, 256, 0, stream>>>(E, SP);     // SP aliases sort bufs; segmean done
  k_fuse2<<<2080, 256, 0, stream>>>(SP, S, E, nb, plist, T, C);
  k_final<<<1, 256, 0, stream>>>(S, T, C, scal, pp, pt, out);
}

// Round 7
// 213.402 us; speedup vs baseline: 1.0776x; 1.0094x over previous
//
#include <hip/hip_runtime.h>
#include <hip/hip_bf16.h>
#include <stdint.h>

typedef unsigned short u16;
typedef float f32x4 __attribute__((ext_vector_type(4)));
typedef short s16x8 __attribute__((ext_vector_type(8)));
typedef u16   u16x8 __attribute__((ext_vector_type(8)));
typedef u16   u16x4 __attribute__((ext_vector_type(4)));
typedef uint32_t u32x4 __attribute__((ext_vector_type(4)));

#define B_      4096
#define D_      256
#define NA_     131072
#define NM_     32768
#define N2_     8192
#define THR4    6.2499950e-6f   /* (0.05 - 1e-8)^4 */
#define K2E     14.426950408889634f  /* 10*log2(e) */

// ---- workspace layout (bytes) ----
#define OFF_CNT_G   0u          // 4096 int
#define OFF_CNT_S   16384u
#define OFF_CUR_G   32768u
#define OFF_CUR_S   49152u
#define OFF_NB      65536u
#define OFF_SCAL    81920u      // f32[0]=llocal f32[1]=lsc int[3]=batch_max
#define OFF_S       98304u      // 8192 f32, atomically accumulated by gemm
#define ZERO_BYTES  131072u     // everything above zeroed each call
#define OFF_T       131072u     // 8192 f32 (fully written by tfix)
#define OFF_C       163840u     // 8192 int (fully written by tfix)
#define OFF_PLIST   196608u     // 4096*32 int
#define OFF_OFFS_G  720896u
#define OFF_OFFS_S  737280u
#define OFF_SORT_G  753664u     // 131072 int
#define OFF_SORT_S  1277952u    // 32768 int
#define OFF_E       1409024u    // 8192*256 bf16 = 4 MB
#define WS_NEED     5603328u

__device__ inline float wave_sum(float v) {
#pragma unroll
  for (int m = 1; m < 64; m <<= 1) v += __shfl_xor(v, m, 64);
  return v;
}
__device__ inline int wave_sum_i(int v) {
#pragma unroll
  for (int m = 1; m < 64; m <<= 1) v += __shfl_xor(v, m, 64);
  return v;
}
__device__ inline u16 f2bf(float f) {
  uint32_t u = __float_as_uint(f);
  uint32_t r = (u + 0x7FFFu + ((u >> 16) & 1u)) >> 16;
  return (u16)r;
}
__device__ inline float bf2f(u16 v) { return __uint_as_float(((uint32_t)v) << 16); }

// async global->LDS, 16B per lane; dst is wave-uniform base, HW adds lane*16
__device__ inline void gload16(const u16* __restrict__ g, u16* l) {
  __builtin_amdgcn_global_load_lds(
      (const __attribute__((address_space(1))) uint32_t*)g,
      (__attribute__((address_space(3))) uint32_t*)l, 16, 0, 0);
}

// ---- zero counters + S ----
__global__ void k_zero(u32x4* __restrict__ p) {
  u32x4 z = {0u, 0u, 0u, 0u};
  p[blockIdx.x * 256 + threadIdx.x] = z;   // 32*256*16B = 131072 B
}

// ---- counts + batch max ----
__global__ void k_count(const int* __restrict__ bg, const int* __restrict__ bs,
                        int* cntg, int* cnts, int* bmax) {
  int i = blockIdx.x * 256 + threadIdx.x;
  int b = -1;
  if (i < NA_) { b = bg[i]; atomicAdd(&cntg[b], 1); }
  if (i < NM_) { atomicAdd(&cnts[bs[i]], 1); }
  int m = b;
#pragma unroll
  for (int k = 1; k < 64; k <<= 1) m = max(m, __shfl_xor(m, k, 64));
  if ((threadIdx.x & 63) == 0 && m >= 0) atomicMax(bmax, m);
}

// ---- exclusive scan of 4096 counts ----
__global__ void k_scan(const int* __restrict__ cntg, const int* __restrict__ cnts,
                       int* offsg, int* offss, int* curg, int* curs) {
  const int* cnt = blockIdx.x == 0 ? cntg : cnts;
  int* offs = blockIdx.x == 0 ? offsg : offss;
  int* cur  = blockIdx.x == 0 ? curg  : curs;
  __shared__ int ls[256];
  int t = threadIdx.x;
  int v[16]; int s = 0;
#pragma unroll
  for (int k = 0; k < 16; k++) { v[k] = cnt[t * 16 + k]; s += v[k]; }
  ls[t] = s;
  __syncthreads();
  for (int off = 1; off < 256; off <<= 1) {
    int add = (t >= off) ? ls[t - off] : 0;
    __syncthreads();
    ls[t] += add;
    __syncthreads();
  }
  int pre = t ? ls[t - 1] : 0;
#pragma unroll
  for (int k = 0; k < 16; k++) { offs[t * 16 + k] = pre; cur[t * 16 + k] = pre; pre += v[k]; }
}

// ---- wave-autonomous segmented mean gather ----
__device__ inline void wave_row_sum(const float* __restrict__ src,
                                    const int* __restrict__ sorted,
                                    int off, int cnt, int lane, f32x4* accs) {
  f32x4 a0 = {0.f,0.f,0.f,0.f}, a1 = a0, a2 = a0, a3 = a0;
  f32x4 a4 = a0, a5 = a0, a6 = a0, a7 = a0;
  for (int base = 0; base < cnt; base += 64) {
    int n = min(cnt - base, 64);
    int idx = (lane < n) ? sorted[off + base + lane] : 0;
    int k = 0;
    for (; k + 7 < n; k += 8) {
      int i0 = __shfl(idx, k,     64), i1 = __shfl(idx, k + 1, 64);
      int i2 = __shfl(idx, k + 2, 64), i3 = __shfl(idx, k + 3, 64);
      int i4 = __shfl(idx, k + 4, 64), i5 = __shfl(idx, k + 5, 64);
      int i6 = __shfl(idx, k + 6, 64), i7 = __shfl(idx, k + 7, 64);
      a0 += *(const f32x4*)(src + (size_t)i0 * D_ + lane * 4);
      a1 += *(const f32x4*)(src + (size_t)i1 * D_ + lane * 4);
      a2 += *(const f32x4*)(src + (size_t)i2 * D_ + lane * 4);
      a3 += *(const f32x4*)(src + (size_t)i3 * D_ + lane * 4);
      a4 += *(const f32x4*)(src + (size_t)i4 * D_ + lane * 4);
      a5 += *(const f32x4*)(src + (size_t)i5 * D_ + lane * 4);
      a6 += *(const f32x4*)(src + (size_t)i6 * D_ + lane * 4);
      a7 += *(const f32x4*)(src + (size_t)i7 * D_ + lane * 4);
    }
    for (; k < n; k++) {
      int i0 = __shfl(idx, k, 64);
      a0 += *(const f32x4*)(src + (size_t)i0 * D_ + lane * 4);
    }
  }
  *accs = ((a0 + a1) + (a2 + a3)) + ((a4 + a5) + (a6 + a7));
}

// ---- fuseA: pairs [0,4096) | scatter [4096,4608) | norm [4608,6656) | lsc [6656,8704) ----
__global__ __launch_bounds__(256) void k_fuseA(
    const int* __restrict__ bg, const int* __restrict__ bs,
    int* __restrict__ curg, int* __restrict__ curs,
    int* __restrict__ sortg, int* __restrict__ sorts,
    const float* __restrict__ gm, const float* __restrict__ scm,
    const float* __restrict__ scs, const float* __restrict__ shp,
    const float* __restrict__ pp,
    u16* __restrict__ E, int* __restrict__ nb, int* __restrict__ plist,
    float* __restrict__ scal) {
  int t = threadIdx.x, w = t >> 6, lane = t & 63;
  int blk = blockIdx.x;

  if (blk < 4096) {               // ---- pairs ----
    int a = blk;
    f32x4 pa = *(const f32x4*)(pp + (size_t)a * 4);
    for (int b = t; b < B_; b += 256) {
      f32x4 pb = *(const f32x4*)(pp + (size_t)b * 4);
      float dx = pa.x - pb.x, dy = pa.y - pb.y, dz = pa.z - pb.z, dw = pa.w - pb.w;
      float d2 = dx * dx + dy * dy + dz * dz + dw * dw;
      if (d2 < THR4) {
        int pos = atomicAdd(&nb[a], 1);
        if (pos < 32) plist[a * 32 + pos] = b;
      }
    }
  } else if (blk < 4608) {        // ---- scatter ----
    int i = (blk - 4096) * 256 + t;
    if (i < NA_) { int b = bg[i]; sortg[atomicAdd(&curg[b], 1)] = i; }
    if (i < NM_) { int b = bs[i]; sorts[atomicAdd(&curs[b], 1)] = i; }
  } else if (blk < 6656) {        // ---- norm -> E bf16 ----
    int r = (blk - 4608) * 4 + w;
    const float* src = (r < B_) ? gm + (size_t)r * D_ : scm + (size_t)(r - B_) * D_;
    f32x4 v = *(const f32x4*)(src + lane * 4);
    float ss = v.x * v.x + v.y * v.y + v.z * v.z + v.w * v.w;
    ss = wave_sum(ss);
    float inv = 1.f / fmaxf(sqrtf(ss), 1e-12f);
    u16x4 o;
    o.x = f2bf(v.x * inv); o.y = f2bf(v.y * inv);
    o.z = f2bf(v.z * inv); o.w = f2bf(v.w * inv);
    *(u16x4*)(E + (size_t)r * D_ + lane * 4) = o;
  } else {                        // ---- lsc ----
    int wg = (blk - 6656) * 4 + w;
    float acc = 0.f;
    for (int r = wg; r < NM_; r += 8192) {
      f32x4 va = *(const f32x4*)(scs + (size_t)r * D_ + lane * 4);
      f32x4 vb = *(const f32x4*)(shp + (size_t)r * D_ + lane * 4);
      float dx = va.x - vb.x, dy = va.y - vb.y, dz = va.z - vb.z, dw = va.w - vb.w;
      float ss = wave_sum(dx * dx + dy * dy + dz * dz + dw * dw);
      if (lane == 0) acc += sqrtf(ss);
    }
    __shared__ float sr4[4];
    if (lane == 0) sr4[w] = acc;
    __syncthreads();
    if (t == 0) atomicAdd(&scal[1], sr4[0] + sr4[1] + sr4[2] + sr4[3]);
  }
}

// ---- fuseB: segmean [0,1024) | gemm [1024,3104) | tfix [3104,5152) ----
// segmean (L3-latency/BW-bound) overlaps gemm (MFMA/VALU-bound) + tfix.
__global__ __launch_bounds__(256) void k_fuseB(
    const u16* __restrict__ E,
    const float* __restrict__ fg, const float* __restrict__ fm,
    const int* __restrict__ cntg, const int* __restrict__ cnts,
    const int* __restrict__ offsg, const int* __restrict__ offss,
    const int* __restrict__ sortg, const int* __restrict__ sorts,
    const int* __restrict__ nb, const int* __restrict__ plist,
    float* __restrict__ S, float* __restrict__ T, int* __restrict__ C,
    float* __restrict__ scal) {
  __shared__ __align__(16) u16 As[128 * 64];
  __shared__ __align__(16) u16 Bs[128 * 64];
  int blk = blockIdx.x;
  int tid = threadIdx.x, lane = tid & 63, wid = tid >> 6;

  if (blk < 1024) {               // ---- segmean (one wave per batch row) ----
    int b = blk * 4 + wid;
    int cg = cntg[b], cs = cnts[b];
    int og = offsg[b], os = offss[b];
    f32x4 sg, ss;
    wave_row_sum(fg, sortg, og, cg, lane, &sg);
    wave_row_sum(fm, sorts, os, cs, lane, &ss);
    float ig = 1.f / fmaxf((float)cg, 1.f);
    float is = 1.f / fmaxf((float)cs, 1.f);
    float dx = sg.x * ig - ss.x * is, dy = sg.y * ig - ss.y * is;
    float dz = sg.z * ig - ss.z * is, dw = sg.w * ig - ss.w * is;
    float v = wave_sum(dx * dx + dy * dy + dz * dz + dw * dw);
    __shared__ float r2[4];
    if (lane == 0) r2[wid] = (cg > 0 && cs > 0) ? sqrtf(v) : 0.f;
    __syncthreads();
    if (tid == 0) {
      float s = r2[0] + r2[1] + r2[2] + r2[3];
      if (s != 0.f) atomicAdd(&scal[0], s);
    }
    return;
  }

  if (blk >= 3104) {              // ---- tfix ----
    int i = (blk - 3104) * 4 + wid;
    int a = i & (B_ - 1);
    int n = min(nb[a], 32);
    u16x4 vi = *(const u16x4*)(E + (size_t)i * D_ + lane * 4);
    float ex = bf2f(vi.x), ey = bf2f(vi.y), ez = bf2f(vi.z), ew = bf2f(vi.w);
    float acc = -(ex * ex + ey * ey + ez * ez + ew * ew);
    for (int k = 0; k < n; k++) {
      int b = plist[a * 32 + k];
      u16x4 v1 = *(const u16x4*)(E + (size_t)b * D_ + lane * 4);
      u16x4 v2 = *(const u16x4*)(E + (size_t)(b + B_) * D_ + lane * 4);
      acc += ex * bf2f(v1.x) + ey * bf2f(v1.y) + ez * bf2f(v1.z) + ew * bf2f(v1.w);
      acc += ex * bf2f(v2.x) + ey * bf2f(v2.y) + ez * bf2f(v2.z) + ew * bf2f(v2.w);
    }
    acc = wave_sum(acc);
    if (lane == 0) { T[i] = 10.0f * acc; C[i] = 2 * n - 1; }
    return;
  }

  // ---- gemm: triangular tile, global_load_lds staging, atomic S accumulation ----
  int t = blk - 1024;
  int bi = (int)((129.0f - sqrtf(129.0f * 129.0f - 8.0f * (float)t)) * 0.5f);
  while ((bi + 1) * (129 - (bi + 1)) / 2 <= t) bi++;
  while (bi * (129 - bi) / 2 > t) bi--;
  int bj = bi + (t - bi * (129 - bi) / 2);

  int row0 = bi * 128, col0 = bj * 128;
  int wr = wid >> 1, wc = wid & 1;

  int rsub = lane >> 3;
  int csw  = (((lane & 7) ^ rsub) << 4) >> 1;

  f32x4 acc[4][4];
#pragma unroll
  for (int mi = 0; mi < 4; mi++)
#pragma unroll
    for (int ni = 0; ni < 4; ni++) {
      f32x4 z = {0.f, 0.f, 0.f, 0.f};
      acc[mi][ni] = z;
    }

  for (int kc = 0; kc < 4; ++kc) {
    __syncthreads();
#pragma unroll
    for (int it = 0; it < 4; it++) {
      int s = wid * 4 + it;
      int r = s * 8 + rsub;
      gload16(E + (size_t)(row0 + r) * D_ + kc * 64 + csw, As + s * 512);
      gload16(E + (size_t)(col0 + r) * D_ + kc * 64 + csw, Bs + s * 512);
    }
    __syncthreads();
#pragma unroll
    for (int kk = 0; kk < 2; ++kk) {
      s16x8 af[4], bfr[4];
#pragma unroll
      for (int mi = 0; mi < 4; mi++) {
        int rA = wr * 64 + mi * 16 + (lane & 15);
        int cbf = kk * 64 + (lane >> 4) * 16;
        int addr = rA * 128 + (cbf ^ ((rA & 7) << 4));
        af[mi] = *(const s16x8*)((const char*)As + addr);
      }
#pragma unroll
      for (int ni = 0; ni < 4; ni++) {
        int rB = wc * 64 + ni * 16 + (lane & 15);
        int cbf = kk * 64 + (lane >> 4) * 16;
        int addr = rB * 128 + (cbf ^ ((rB & 7) << 4));
        bfr[ni] = *(const s16x8*)((const char*)Bs + addr);
      }
#pragma unroll
      for (int mi = 0; mi < 4; mi++)
#pragma unroll
        for (int ni = 0; ni < 4; ni++)
          acc[mi][ni] = __builtin_amdgcn_mfma_f32_16x16x32_bf16(af[mi], bfr[ni], acc[mi][ni], 0, 0, 0);
    }
  }

  // epilogue: exp(10a-10)=exp2(a*K2E-K2E); rows + (off-diag) cols -> atomic S
  int g = lane >> 4, cl = lane & 15;
  float colsum[4] = {0.f, 0.f, 0.f, 0.f};
#pragma unroll
  for (int mi = 0; mi < 4; mi++) {
#pragma unroll
    for (int reg = 0; reg < 4; ++reg) {
      int gi = row0 + wr * 64 + mi * 16 + g * 4 + reg;
      float vs = 0.f;
#pragma unroll
      for (int ni = 0; ni < 4; ni++) {
        float e = exp2f(acc[mi][ni][reg] * K2E - K2E);
        vs += e;
        colsum[ni] += e;
      }
#pragma unroll
      for (int m = 1; m < 16; m <<= 1) vs += __shfl_xor(vs, m, 64);
      if (cl == 0) atomicAdd(&S[gi], vs);
    }
  }
  if (bi != bj) {
#pragma unroll
    for (int ni = 0; ni < 4; ni++) {
      float cs = colsum[ni];
      cs += __shfl_xor(cs, 16, 64);
      cs += __shfl_xor(cs, 32, 64);
      if (g == 0) atomicAdd(&S[col0 + wc * 64 + ni * 16 + cl], cs);
    }
  }
}

// ---- final combine (+ l_prop fused) ----
__global__ void k_final(const float* __restrict__ S, const float* __restrict__ T,
                        const int* __restrict__ C, const float* __restrict__ scal,
                        const float* __restrict__ pp, const float* __restrict__ pt,
                        float* __restrict__ out) {
  float sp = 0.f;
  for (int i = threadIdx.x; i < B_ * 4; i += 256) {
    float d = pp[i] - pt[i];
    sp += d * d;
  }
  float rls = 0.f; int nv = 0;
  for (int i = threadIdx.x; i < N2_; i += 256) {
    int ci = C[i];
    if (ci > 0) { rls += (10.0f + logf(S[i])) - T[i] / (float)ci; nv++; }
  }
  rls = wave_sum(rls);
  sp  = wave_sum(sp);
  nv  = wave_sum_i(nv);
  __shared__ float r1[4], r3[4]; __shared__ int r2[4];
  int lane = threadIdx.x & 63, w = threadIdx.x >> 6;
  if (lane == 0) { r1[w] = rls; r2[w] = nv; r3[w] = sp; }
  __syncthreads();
  if (threadIdx.x == 0) {
    float rtot = r1[0] + r1[1] + r1[2] + r1[3];
    int nvt = r2[0] + r2[1] + r2[2] + r2[3];
    float sptot = r3[0] + r3[1] + r3[2] + r3[3];
    float l_contr = nvt > 0 ? rtot / (float)nvt : 0.f;
    int bmax = ((const int*)scal)[3];
    float bs = (float)bmax + 1.0f;
    float l_local_g = scal[0] / bs;
    float l_sc = scal[1] / (float)NM_;
    float l_prop = sptot / (float)(B_ * 4);
    float l_hes = 1.0f * l_local_g + 0.8f * l_contr + 1.0f * l_sc + 0.8f * l_contr + 0.5f * l_prop;
    out[0] = l_hes; out[1] = l_local_g; out[2] = l_contr;
    out[3] = l_sc;  out[4] = l_contr;   out[5] = l_prop;
  }
}

extern "C" void kernel_launch(void* const* d_in, const int* in_sizes, int n_in,
                              void* d_out, int out_size, void* d_ws, size_t ws_size,
                              hipStream_t stream) {
  if (ws_size < WS_NEED) return;
  const float* gm  = (const float*)d_in[0];
  const float* fg  = (const float*)d_in[1];
  const float* scm = (const float*)d_in[2];
  const float* scs = (const float*)d_in[3];
  const float* mot = (const float*)d_in[4];
  const float* shp = (const float*)d_in[5];
  const float* pp  = (const float*)d_in[6];
  const float* pt  = (const float*)d_in[7];
  const int* bg = (const int*)d_in[8];
  const int* bs = (const int*)d_in[9];
  float* out = (float*)d_out;
  char* ws = (char*)d_ws;

  int* cntg  = (int*)(ws + OFF_CNT_G);
  int* cnts  = (int*)(ws + OFF_CNT_S);
  int* curg  = (int*)(ws + OFF_CUR_G);
  int* curs  = (int*)(ws + OFF_CUR_S);
  int* nb    = (int*)(ws + OFF_NB);
  float* scal = (float*)(ws + OFF_SCAL);
  float* S   = (float*)(ws + OFF_S);
  float* T   = (float*)(ws + OFF_T);
  int* C     = (int*)(ws + OFF_C);
  int* plist = (int*)(ws + OFF_PLIST);
  int* offsg = (int*)(ws + OFF_OFFS_G);
  int* offss = (int*)(ws + OFF_OFFS_S);
  int* sortg = (int*)(ws + OFF_SORT_G);
  int* sorts = (int*)(ws + OFF_SORT_S);
  u16* E     = (u16*)(ws + OFF_E);

  k_zero<<<32, 256, 0, stream>>>((u32x4*)ws);
  k_count<<<512, 256, 0, stream>>>(bg, bs, cntg, cnts, (int*)scal + 3);
  k_scan<<<2, 256, 0, stream>>>(cntg, cnts, offsg, offss, curg, curs);
  k_fuseA<<<8704, 256, 0, stream>>>(bg, bs, curg, curs, sortg, sorts,
                                    gm, scm, scs, shp, pp, E, nb, plist, scal);
  k_fuseB<<<5152, 256, 0, stream>>>(E, fg, mot, cntg, cnts, offsg, offss,
                                    sortg, sorts, nb, plist, S, T, C, scal);
  k_final<<<1, 256, 0, stream>>>(S, T, C, scal, pp, pt, out);
}

// Round 8
// 212.630 us; speedup vs baseline: 1.0816x; 1.0036x over previous
//
#include <hip/hip_runtime.h>
#include <hip/hip_bf16.h>
#include <stdint.h>

typedef unsigned short u16;
typedef float f32x4 __attribute__((ext_vector_type(4)));
typedef short s16x8 __attribute__((ext_vector_type(8)));
typedef u16   u16x8 __attribute__((ext_vector_type(8)));
typedef u16   u16x4 __attribute__((ext_vector_type(4)));
typedef uint32_t u32x4 __attribute__((ext_vector_type(4)));

#define B_      4096
#define D_      256
#define NA_     131072
#define NM_     32768
#define N2_     8192
#define THR4    6.2499950e-6f   /* (0.05 - 1e-8)^4 */
#define K2E     14.426950408889634f  /* 10*log2(e) */

// fuseB role interleave (Bresenham spread): S=segmean G=gemm T=tfix
#define NS_   1024
#define NG_   2080
#define NT_   256
#define NTOT_ 3360
#define NR_   2336   /* NTOT_ - NS_ */

// ---- workspace layout (bytes) ----
#define OFF_CNT_G   0u
#define OFF_CNT_S   16384u
#define OFF_CUR_G   32768u
#define OFF_CUR_S   49152u
#define OFF_NB      65536u
#define OFF_SCAL    81920u      // f32[0]=llocal f32[1]=lsc int[3]=batch_max
#define OFF_S       98304u      // 8192 f32, atomically accumulated by gemm
#define ZERO_BYTES  131072u
#define OFF_T       131072u
#define OFF_C       163840u
#define OFF_PLIST   196608u
#define OFF_OFFS_G  720896u
#define OFF_OFFS_S  737280u
#define OFF_SORT_G  753664u
#define OFF_SORT_S  1277952u
#define OFF_E       1409024u
#define WS_NEED     5603328u

__device__ inline float wave_sum(float v) {
#pragma unroll
  for (int m = 1; m < 64; m <<= 1) v += __shfl_xor(v, m, 64);
  return v;
}
__device__ inline int wave_sum_i(int v) {
#pragma unroll
  for (int m = 1; m < 64; m <<= 1) v += __shfl_xor(v, m, 64);
  return v;
}
__device__ inline u16 f2bf(float f) {
  uint32_t u = __float_as_uint(f);
  uint32_t r = (u + 0x7FFFu + ((u >> 16) & 1u)) >> 16;
  return (u16)r;
}
__device__ inline float bf2f(u16 v) { return __uint_as_float(((uint32_t)v) << 16); }

__device__ inline void gload16(const u16* __restrict__ g, u16* l) {
  __builtin_amdgcn_global_load_lds(
      (const __attribute__((address_space(1))) uint32_t*)g,
      (__attribute__((address_space(3))) uint32_t*)l, 16, 0, 0);
}

// ---- zero counters + S ----
__global__ void k_zero(u32x4* __restrict__ p) {
  u32x4 z = {0u, 0u, 0u, 0u};
  p[blockIdx.x * 256 + threadIdx.x] = z;   // 32*256*16B = 131072 B
}

// ---- kA: count [0,512) | pairs [512,4608) | norm [4608,6656) | lsc [6656,8704) ----
__global__ __launch_bounds__(256) void k_fuseA(
    const int* __restrict__ bg, const int* __restrict__ bs,
    int* __restrict__ cntg, int* __restrict__ cnts, int* __restrict__ bmax,
    const float* __restrict__ gm, const float* __restrict__ scm,
    const float* __restrict__ scs, const float* __restrict__ shp,
    const float* __restrict__ pp,
    u16* __restrict__ E, int* __restrict__ nb, int* __restrict__ plist,
    float* __restrict__ scal) {
  int t = threadIdx.x, w = t >> 6, lane = t & 63;
  int blk = blockIdx.x;

  if (blk < 512) {                // ---- count + batch max ----
    int i = blk * 256 + t;
    int b = -1;
    if (i < NA_) { b = bg[i]; atomicAdd(&cntg[b], 1); }
    if (i < NM_) { atomicAdd(&cnts[bs[i]], 1); }
    int m = b;
#pragma unroll
    for (int k = 1; k < 64; k <<= 1) m = max(m, __shfl_xor(m, k, 64));
    if ((t & 63) == 0 && m >= 0) atomicMax(bmax, m);
  } else if (blk < 4608) {        // ---- pairs ----
    int a = blk - 512;
    f32x4 pa = *(const f32x4*)(pp + (size_t)a * 4);
    for (int b = t; b < B_; b += 256) {
      f32x4 pb = *(const f32x4*)(pp + (size_t)b * 4);
      float dx = pa.x - pb.x, dy = pa.y - pb.y, dz = pa.z - pb.z, dw = pa.w - pb.w;
      float d2 = dx * dx + dy * dy + dz * dz + dw * dw;
      if (d2 < THR4) {
        int pos = atomicAdd(&nb[a], 1);
        if (pos < 32) plist[a * 32 + pos] = b;
      }
    }
  } else if (blk < 6656) {        // ---- norm -> E bf16 ----
    int r = (blk - 4608) * 4 + w;
    const float* src = (r < B_) ? gm + (size_t)r * D_ : scm + (size_t)(r - B_) * D_;
    f32x4 v = *(const f32x4*)(src + lane * 4);
    float ss = v.x * v.x + v.y * v.y + v.z * v.z + v.w * v.w;
    ss = wave_sum(ss);
    float inv = 1.f / fmaxf(sqrtf(ss), 1e-12f);
    u16x4 o;
    o.x = f2bf(v.x * inv); o.y = f2bf(v.y * inv);
    o.z = f2bf(v.z * inv); o.w = f2bf(v.w * inv);
    *(u16x4*)(E + (size_t)r * D_ + lane * 4) = o;
  } else {                        // ---- lsc ----
    int wg = (blk - 6656) * 4 + w;
    float acc = 0.f;
    for (int r = wg; r < NM_; r += 8192) {
      f32x4 va = *(const f32x4*)(scs + (size_t)r * D_ + lane * 4);
      f32x4 vb = *(const f32x4*)(shp + (size_t)r * D_ + lane * 4);
      float dx = va.x - vb.x, dy = va.y - vb.y, dz = va.z - vb.z, dw = va.w - vb.w;
      float ss = wave_sum(dx * dx + dy * dy + dz * dz + dw * dw);
      if (lane == 0) acc += sqrtf(ss);
    }
    __shared__ float sr4[4];
    if (lane == 0) sr4[w] = acc;
    __syncthreads();
    if (t == 0) atomicAdd(&scal[1], sr4[0] + sr4[1] + sr4[2] + sr4[3]);
  }
}

// ---- exclusive scan of 4096 counts ----
__global__ void k_scan(const int* __restrict__ cntg, const int* __restrict__ cnts,
                       int* offsg, int* offss, int* curg, int* curs) {
  const int* cnt = blockIdx.x == 0 ? cntg : cnts;
  int* offs = blockIdx.x == 0 ? offsg : offss;
  int* cur  = blockIdx.x == 0 ? curg  : curs;
  __shared__ int ls[256];
  int t = threadIdx.x;
  int v[16]; int s = 0;
#pragma unroll
  for (int k = 0; k < 16; k++) { v[k] = cnt[t * 16 + k]; s += v[k]; }
  ls[t] = s;
  __syncthreads();
  for (int off = 1; off < 256; off <<= 1) {
    int add = (t >= off) ? ls[t - off] : 0;
    __syncthreads();
    ls[t] += add;
    __syncthreads();
  }
  int pre = t ? ls[t - 1] : 0;
#pragma unroll
  for (int k = 0; k < 16; k++) { offs[t * 16 + k] = pre; cur[t * 16 + k] = pre; pre += v[k]; }
}

// ---- scatter into sorted order ----
__global__ void k_scatter(const int* __restrict__ bg, const int* __restrict__ bs,
                          int* curg, int* curs, int* sortg, int* sorts) {
  int i = blockIdx.x * 256 + threadIdx.x;
  if (i < NA_) { int b = bg[i]; sortg[atomicAdd(&curg[b], 1)] = i; }
  if (i < NM_) { int b = bs[i]; sorts[atomicAdd(&curs[b], 1)] = i; }
}

// ---- wave-autonomous segmented mean gather ----
__device__ inline void wave_row_sum(const float* __restrict__ src,
                                    const int* __restrict__ sorted,
                                    int off, int cnt, int lane, f32x4* accs) {
  f32x4 a0 = {0.f,0.f,0.f,0.f}, a1 = a0, a2 = a0, a3 = a0;
  f32x4 a4 = a0, a5 = a0, a6 = a0, a7 = a0;
  for (int base = 0; base < cnt; base += 64) {
    int n = min(cnt - base, 64);
    int idx = (lane < n) ? sorted[off + base + lane] : 0;
    int k = 0;
    for (; k + 7 < n; k += 8) {
      int i0 = __shfl(idx, k,     64), i1 = __shfl(idx, k + 1, 64);
      int i2 = __shfl(idx, k + 2, 64), i3 = __shfl(idx, k + 3, 64);
      int i4 = __shfl(idx, k + 4, 64), i5 = __shfl(idx, k + 5, 64);
      int i6 = __shfl(idx, k + 6, 64), i7 = __shfl(idx, k + 7, 64);
      a0 += *(const f32x4*)(src + (size_t)i0 * D_ + lane * 4);
      a1 += *(const f32x4*)(src + (size_t)i1 * D_ + lane * 4);
      a2 += *(const f32x4*)(src + (size_t)i2 * D_ + lane * 4);
      a3 += *(const f32x4*)(src + (size_t)i3 * D_ + lane * 4);
      a4 += *(const f32x4*)(src + (size_t)i4 * D_ + lane * 4);
      a5 += *(const f32x4*)(src + (size_t)i5 * D_ + lane * 4);
      a6 += *(const f32x4*)(src + (size_t)i6 * D_ + lane * 4);
      a7 += *(const f32x4*)(src + (size_t)i7 * D_ + lane * 4);
    }
    for (; k < n; k++) {
      int i0 = __shfl(idx, k, 64);
      a0 += *(const f32x4*)(src + (size_t)i0 * D_ + lane * 4);
    }
  }
  *accs = ((a0 + a1) + (a2 + a3)) + ((a4 + a5) + (a6 + a7));
}

// ---- fuseB: roles Bresenham-interleaved across blockIdx so each CU holds a mix ----
__global__ __launch_bounds__(256) void k_fuseB(
    const u16* __restrict__ E,
    const float* __restrict__ fg, const float* __restrict__ fm,
    const int* __restrict__ cntg, const int* __restrict__ cnts,
    const int* __restrict__ offsg, const int* __restrict__ offss,
    const int* __restrict__ sortg, const int* __restrict__ sorts,
    const int* __restrict__ nb, const int* __restrict__ plist,
    float* __restrict__ S, float* __restrict__ T, int* __restrict__ C,
    float* __restrict__ scal) {
  __shared__ __align__(16) u16 As[128 * 64];
  __shared__ __align__(16) u16 Bs[128 * 64];
  int blk = blockIdx.x;
  int tid = threadIdx.x, lane = tid & 63, wid = tid >> 6;

  // role decode: S iff (blk*NS)%NTOT < NS; remainder splits G/T the same way
  int64_t p = (int64_t)blk * NS_;
  int srem = (int)(p % NTOT_);
  if (srem < NS_) {               // ---- segmean (sid in [0,1024)) ----
    int sid = (int)(p / NTOT_);
    int b = sid * 4 + wid;
    int cg = cntg[b], cs = cnts[b];
    int og = offsg[b], os = offss[b];
    f32x4 sg, ss;
    wave_row_sum(fg, sortg, og, cg, lane, &sg);
    wave_row_sum(fm, sorts, os, cs, lane, &ss);
    float ig = 1.f / fmaxf((float)cg, 1.f);
    float is = 1.f / fmaxf((float)cs, 1.f);
    float dx = sg.x * ig - ss.x * is, dy = sg.y * ig - ss.y * is;
    float dz = sg.z * ig - ss.z * is, dw = sg.w * ig - ss.w * is;
    float v = wave_sum(dx * dx + dy * dy + dz * dz + dw * dw);
    __shared__ float r2[4];
    if (lane == 0) r2[wid] = (cg > 0 && cs > 0) ? sqrtf(v) : 0.f;
    __syncthreads();
    if (tid == 0) {
      float s = r2[0] + r2[1] + r2[2] + r2[3];
      if (s != 0.f) atomicAdd(&scal[0], s);
    }
    return;
  }

  int r = blk - (int)((p + NTOT_ - 1) / NTOT_);   // rank among non-S: [0, NR_)
  int64_t q = (int64_t)r * NG_;
  int grem = (int)(q % NR_);

  if (grem >= NG_) {              // ---- tfix (tix in [0,256), 8 rows/wave) ----
    int tix = r - (int)((q + NR_ - 1) / NR_);
#pragma unroll
    for (int k8 = 0; k8 < 8; k8++) {
      int i = tix * 32 + wid * 8 + k8;
      int a = i & (B_ - 1);
      int n = min(nb[a], 32);
      u16x4 vi = *(const u16x4*)(E + (size_t)i * D_ + lane * 4);
      float ex = bf2f(vi.x), ey = bf2f(vi.y), ez = bf2f(vi.z), ew = bf2f(vi.w);
      float acc = -(ex * ex + ey * ey + ez * ez + ew * ew);
      for (int k = 0; k < n; k++) {
        int b = plist[a * 32 + k];
        u16x4 v1 = *(const u16x4*)(E + (size_t)b * D_ + lane * 4);
        u16x4 v2 = *(const u16x4*)(E + (size_t)(b + B_) * D_ + lane * 4);
        acc += ex * bf2f(v1.x) + ey * bf2f(v1.y) + ez * bf2f(v1.z) + ew * bf2f(v1.w);
        acc += ex * bf2f(v2.x) + ey * bf2f(v2.y) + ez * bf2f(v2.z) + ew * bf2f(v2.w);
      }
      acc = wave_sum(acc);
      if (lane == 0) { T[i] = 10.0f * acc; C[i] = 2 * n - 1; }
    }
    return;
  }

  // ---- gemm (gid in [0,2080)) ----
  int t = (int)(q / NR_);
  int bi = (int)((129.0f - sqrtf(129.0f * 129.0f - 8.0f * (float)t)) * 0.5f);
  while ((bi + 1) * (129 - (bi + 1)) / 2 <= t) bi++;
  while (bi * (129 - bi) / 2 > t) bi--;
  int bj = bi + (t - bi * (129 - bi) / 2);

  int row0 = bi * 128, col0 = bj * 128;
  int wr = wid >> 1, wc = wid & 1;

  int rsub = lane >> 3;
  int csw  = (((lane & 7) ^ rsub) << 4) >> 1;

  f32x4 acc[4][4];
#pragma unroll
  for (int mi = 0; mi < 4; mi++)
#pragma unroll
    for (int ni = 0; ni < 4; ni++) {
      f32x4 z = {0.f, 0.f, 0.f, 0.f};
      acc[mi][ni] = z;
    }

  for (int kc = 0; kc < 4; ++kc) {
    __syncthreads();
#pragma unroll
    for (int it = 0; it < 4; it++) {
      int s = wid * 4 + it;
      int rr = s * 8 + rsub;
      gload16(E + (size_t)(row0 + rr) * D_ + kc * 64 + csw, As + s * 512);
      gload16(E + (size_t)(col0 + rr) * D_ + kc * 64 + csw, Bs + s * 512);
    }
    __syncthreads();
#pragma unroll
    for (int kk = 0; kk < 2; ++kk) {
      s16x8 af[4], bfr[4];
#pragma unroll
      for (int mi = 0; mi < 4; mi++) {
        int rA = wr * 64 + mi * 16 + (lane & 15);
        int cbf = kk * 64 + (lane >> 4) * 16;
        int addr = rA * 128 + (cbf ^ ((rA & 7) << 4));
        af[mi] = *(const s16x8*)((const char*)As + addr);
      }
#pragma unroll
      for (int ni = 0; ni < 4; ni++) {
        int rB = wc * 64 + ni * 16 + (lane & 15);
        int cbf = kk * 64 + (lane >> 4) * 16;
        int addr = rB * 128 + (cbf ^ ((rB & 7) << 4));
        bfr[ni] = *(const s16x8*)((const char*)Bs + addr);
      }
#pragma unroll
      for (int mi = 0; mi < 4; mi++)
#pragma unroll
        for (int ni = 0; ni < 4; ni++)
          acc[mi][ni] = __builtin_amdgcn_mfma_f32_16x16x32_bf16(af[mi], bfr[ni], acc[mi][ni], 0, 0, 0);
    }
  }

  int g = lane >> 4, cl = lane & 15;
  float colsum[4] = {0.f, 0.f, 0.f, 0.f};
#pragma unroll
  for (int mi = 0; mi < 4; mi++) {
#pragma unroll
    for (int reg = 0; reg < 4; ++reg) {
      int gi = row0 + wr * 64 + mi * 16 + g * 4 + reg;
      float vs = 0.f;
#pragma unroll
      for (int ni = 0; ni < 4; ni++) {
        float e = exp2f(acc[mi][ni][reg] * K2E - K2E);
        vs += e;
        colsum[ni] += e;
      }
#pragma unroll
      for (int m = 1; m < 16; m <<= 1) vs += __shfl_xor(vs, m, 64);
      if (cl == 0) atomicAdd(&S[gi], vs);
    }
  }
  if (bi != bj) {
#pragma unroll
    for (int ni = 0; ni < 4; ni++) {
      float cs = colsum[ni];
      cs += __shfl_xor(cs, 16, 64);
      cs += __shfl_xor(cs, 32, 64);
      if (g == 0) atomicAdd(&S[col0 + wc * 64 + ni * 16 + cl], cs);
    }
  }
}

// ---- final combine (+ l_prop fused) ----
__global__ void k_final(const float* __restrict__ S, const float* __restrict__ T,
                        const int* __restrict__ C, const float* __restrict__ scal,
                        const float* __restrict__ pp, const float* __restrict__ pt,
                        float* __restrict__ out) {
  float sp = 0.f;
  for (int i = threadIdx.x; i < B_ * 4; i += 256) {
    float d = pp[i] - pt[i];
    sp += d * d;
  }
  float rls = 0.f; int nv = 0;
  for (int i = threadIdx.x; i < N2_; i += 256) {
    int ci = C[i];
    if (ci > 0) { rls += (10.0f + logf(S[i])) - T[i] / (float)ci; nv++; }
  }
  rls = wave_sum(rls);
  sp  = wave_sum(sp);
  nv  = wave_sum_i(nv);
  __shared__ float r1[4], r3[4]; __shared__ int r2[4];
  int lane = threadIdx.x & 63, w = threadIdx.x >> 6;
  if (lane == 0) { r1[w] = rls; r2[w] = nv; r3[w] = sp; }
  __syncthreads();
  if (threadIdx.x == 0) {
    float rtot = r1[0] + r1[1] + r1[2] + r1[3];
    int nvt = r2[0] + r2[1] + r2[2] + r2[3];
    float sptot = r3[0] + r3[1] + r3[2] + r3[3];
    float l_contr = nvt > 0 ? rtot / (float)nvt : 0.f;
    int bmax = ((const int*)scal)[3];
    float bs = (float)bmax + 1.0f;
    float l_local_g = scal[0] / bs;
    float l_sc = scal[1] / (float)NM_;
    float l_prop = sptot / (float)(B_ * 4);
    float l_hes = 1.0f * l_local_g + 0.8f * l_contr + 1.0f * l_sc + 0.8f * l_contr + 0.5f * l_prop;
    out[0] = l_hes; out[1] = l_local_g; out[2] = l_contr;
    out[3] = l_sc;  out[4] = l_contr;   out[5] = l_prop;
  }
}

extern "C" void kernel_launch(void* const* d_in, const int* in_sizes, int n_in,
                              void* d_out, int out_size, void* d_ws, size_t ws_size,
                              hipStream_t stream) {
  if (ws_size < WS_NEED) return;
  const float* gm  = (const float*)d_in[0];
  const float* fg  = (const float*)d_in[1];
  const float* scm = (const float*)d_in[2];
  const float* scs = (const float*)d_in[3];
  const float* mot = (const float*)d_in[4];
  const float* shp = (const float*)d_in[5];
  const float* pp  = (const float*)d_in[6];
  const float* pt  = (const float*)d_in[7];
  const int* bg = (const int*)d_in[8];
  const int* bs = (const int*)d_in[9];
  float* out = (float*)d_out;
  char* ws = (char*)d_ws;

  int* cntg  = (int*)(ws + OFF_CNT_G);
  int* cnts  = (int*)(ws + OFF_CNT_S);
  int* curg  = (int*)(ws + OFF_CUR_G);
  int* curs  = (int*)(ws + OFF_CUR_S);
  int* nb    = (int*)(ws + OFF_NB);
  float* scal = (float*)(ws + OFF_SCAL);
  float* S   = (float*)(ws + OFF_S);
  float* T   = (float*)(ws + OFF_T);
  int* C     = (int*)(ws + OFF_C);
  int* plist = (int*)(ws + OFF_PLIST);
  int* offsg = (int*)(ws + OFF_OFFS_G);
  int* offss = (int*)(ws + OFF_OFFS_S);
  int* sortg = (int*)(ws + OFF_SORT_G);
  int* sorts = (int*)(ws + OFF_SORT_S);
  u16* E     = (u16*)(ws + OFF_E);

  k_zero<<<32, 256, 0, stream>>>((u32x4*)ws);
  k_fuseA<<<8704, 256, 0, stream>>>(bg, bs, cntg, cnts, (int*)scal + 3,
                                    gm, scm, scs, shp, pp, E, nb, plist, scal);
  k_scan<<<2, 256, 0, stream>>>(cntg, cnts, offsg, offss, curg, curs);
  k_scatter<<<512, 256, 0, stream>>>(bg, bs, curg, curs, sortg, sorts);
  k_fuseB<<<NTOT_, 256, 0, stream>>>(E, fg, mot, cntg, cnts, offsg, offss,
                                     sortg, sorts, nb, plist, S, T, C, scal);
  k_final<<<1, 256, 0, stream>>>(S, T, C, scal, pp, pt, out);
}

// Round 9
// 202.794 us; speedup vs baseline: 1.1340x; 1.0485x over previous
//
#include <hip/hip_runtime.h>
#include <hip/hip_bf16.h>
#include <stdint.h>

typedef unsigned short u16;
typedef float f32x4 __attribute__((ext_vector_type(4)));
typedef short s16x8 __attribute__((ext_vector_type(8)));
typedef u16   u16x8 __attribute__((ext_vector_type(8)));
typedef u16   u16x4 __attribute__((ext_vector_type(4)));
typedef uint32_t u32x4 __attribute__((ext_vector_type(4)));

#define B_      4096
#define D_      256
#define NA_     131072
#define NM_     32768
#define N2_     8192
#define THR4    6.2499950e-6f   /* (0.05 - 1e-8)^4 */
#define K2E     14.426950408889634f  /* 10*log2(e) */
#define CAPG    96
#define CAPS    40

// fuseB role interleave (Bresenham spread): S=segmean G=gemm T=tfix
#define NS_   1024
#define NG_   2080
#define NT_   256
#define NTOT_ 3360
#define NR_   2336   /* NTOT_ - NS_ */

// ---- workspace layout (bytes) ----
#define OFF_CNT_G   0u          // 4096 int
#define OFF_CNT_S   16384u      // 4096 int
#define OFF_NB      32768u      // 4096 int
#define OFF_SCAL    49152u      // f32[0]=llocal f32[1]=lsc int[3]=batch_max
#define OFF_S       65536u      // 8192 f32, atomically accumulated by gemm
#define ZERO_BYTES  98304u      // all of the above zeroed each call
#define OFF_T       98304u      // 8192 f32 (fully written by tfix)
#define OFF_C       131072u     // 8192 int (fully written by tfix)
#define OFF_PLIST   163840u     // 4096*32 int
#define OFF_LIST_G  688128u     // 4096*96 int
#define OFF_LIST_S  2260992u    // 4096*40 int
#define OFF_E       2916352u    // 8192*256 bf16 = 4 MB
#define WS_NEED     7110656u

__device__ inline float wave_sum(float v) {
#pragma unroll
  for (int m = 1; m < 64; m <<= 1) v += __shfl_xor(v, m, 64);
  return v;
}
__device__ inline int wave_sum_i(int v) {
#pragma unroll
  for (int m = 1; m < 64; m <<= 1) v += __shfl_xor(v, m, 64);
  return v;
}
__device__ inline u16 f2bf(float f) {
  uint32_t u = __float_as_uint(f);
  uint32_t r = (u + 0x7FFFu + ((u >> 16) & 1u)) >> 16;
  return (u16)r;
}
__device__ inline float bf2f(u16 v) { return __uint_as_float(((uint32_t)v) << 16); }

// non-temporal f32x4 load: nt flag keeps streaming data from evicting L2 (E tiles)
__device__ inline f32x4 ldnt4(const float* p) {
  return __builtin_nontemporal_load((const f32x4*)p);
}

__device__ inline void gload16(const u16* __restrict__ g, u16* l) {
  __builtin_amdgcn_global_load_lds(
      (const __attribute__((address_space(1))) uint32_t*)g,
      (__attribute__((address_space(3))) uint32_t*)l, 16, 0, 0);
}

// ---- zero counters + S ----
__global__ void k_zero(u32x4* __restrict__ p) {
  u32x4 z = {0u, 0u, 0u, 0u};
  p[blockIdx.x * 256 + threadIdx.x] = z;   // 24*256*16B = 98304 B
}

// ---- kA: append-lists [0,512) | pairs [512,4608) | norm [4608,6656) | lsc [6656,8704) ----
__global__ __launch_bounds__(256) void k_fuseA(
    const int* __restrict__ bg, const int* __restrict__ bs,
    int* __restrict__ cntg, int* __restrict__ cnts, int* __restrict__ bmax,
    int* __restrict__ listg, int* __restrict__ lists,
    const float* __restrict__ gm, const float* __restrict__ scm,
    const float* __restrict__ scs, const float* __restrict__ shp,
    const float* __restrict__ pp,
    u16* __restrict__ E, int* __restrict__ nb, int* __restrict__ plist,
    float* __restrict__ scal) {
  int t = threadIdx.x, w = t >> 6, lane = t & 63;
  int blk = blockIdx.x;

  if (blk < 512) {                // ---- atomic-append bucket lists ----
    int i = blk * 256 + t;
    int b = -1;
    if (i < NA_) {
      b = bg[i];
      int pos = atomicAdd(&cntg[b], 1);
      if (pos < CAPG) listg[b * CAPG + pos] = i;
    }
    if (i < NM_) {
      int b2 = bs[i];
      int pos = atomicAdd(&cnts[b2], 1);
      if (pos < CAPS) lists[b2 * CAPS + pos] = i;
    }
    int m = b;
#pragma unroll
    for (int k = 1; k < 64; k <<= 1) m = max(m, __shfl_xor(m, k, 64));
    if ((t & 63) == 0 && m >= 0) atomicMax(bmax, m);
  } else if (blk < 4608) {        // ---- pairs (pp is 64KB, cached) ----
    int a = blk - 512;
    f32x4 pa = *(const f32x4*)(pp + (size_t)a * 4);
    for (int b = t; b < B_; b += 256) {
      f32x4 pb = *(const f32x4*)(pp + (size_t)b * 4);
      float dx = pa.x - pb.x, dy = pa.y - pb.y, dz = pa.z - pb.z, dw = pa.w - pb.w;
      float d2 = dx * dx + dy * dy + dz * dz + dw * dw;
      if (d2 < THR4) {
        int pos = atomicAdd(&nb[a], 1);
        if (pos < 32) plist[a * 32 + pos] = b;
      }
    }
  } else if (blk < 6656) {        // ---- norm -> E bf16 (streaming src: NT) ----
    int r = (blk - 4608) * 4 + w;
    const float* src = (r < B_) ? gm + (size_t)r * D_ : scm + (size_t)(r - B_) * D_;
    f32x4 v = ldnt4(src + lane * 4);
    float ss = v.x * v.x + v.y * v.y + v.z * v.z + v.w * v.w;
    ss = wave_sum(ss);
    float inv = 1.f / fmaxf(sqrtf(ss), 1e-12f);
    u16x4 o;
    o.x = f2bf(v.x * inv); o.y = f2bf(v.y * inv);
    o.z = f2bf(v.z * inv); o.w = f2bf(v.w * inv);
    *(u16x4*)(E + (size_t)r * D_ + lane * 4) = o;
  } else {                        // ---- lsc (streaming: NT) ----
    int wg = (blk - 6656) * 4 + w;
    float acc = 0.f;
    for (int r = wg; r < NM_; r += 8192) {
      f32x4 va = ldnt4(scs + (size_t)r * D_ + lane * 4);
      f32x4 vb = ldnt4(shp + (size_t)r * D_ + lane * 4);
      float dx = va.x - vb.x, dy = va.y - vb.y, dz = va.z - vb.z, dw = va.w - vb.w;
      float ss = wave_sum(dx * dx + dy * dy + dz * dz + dw * dw);
      if (lane == 0) acc += sqrtf(ss);
    }
    __shared__ float sr4[4];
    if (lane == 0) sr4[w] = acc;
    __syncthreads();
    if (t == 0) atomicAdd(&scal[1], sr4[0] + sr4[1] + sr4[2] + sr4[3]);
  }
}

// ---- wave-autonomous segmented mean gather (NT row loads) ----
__device__ inline void wave_row_sum(const float* __restrict__ src,
                                    const int* __restrict__ list,
                                    int off, int cnt, int lane, f32x4* accs) {
  f32x4 a0 = {0.f,0.f,0.f,0.f}, a1 = a0, a2 = a0, a3 = a0;
  f32x4 a4 = a0, a5 = a0, a6 = a0, a7 = a0;
  for (int base = 0; base < cnt; base += 64) {
    int n = min(cnt - base, 64);
    int idx = (lane < n) ? list[off + base + lane] : 0;
    int k = 0;
    for (; k + 7 < n; k += 8) {
      int i0 = __shfl(idx, k,     64), i1 = __shfl(idx, k + 1, 64);
      int i2 = __shfl(idx, k + 2, 64), i3 = __shfl(idx, k + 3, 64);
      int i4 = __shfl(idx, k + 4, 64), i5 = __shfl(idx, k + 5, 64);
      int i6 = __shfl(idx, k + 6, 64), i7 = __shfl(idx, k + 7, 64);
      a0 += ldnt4(src + (size_t)i0 * D_ + lane * 4);
      a1 += ldnt4(src + (size_t)i1 * D_ + lane * 4);
      a2 += ldnt4(src + (size_t)i2 * D_ + lane * 4);
      a3 += ldnt4(src + (size_t)i3 * D_ + lane * 4);
      a4 += ldnt4(src + (size_t)i4 * D_ + lane * 4);
      a5 += ldnt4(src + (size_t)i5 * D_ + lane * 4);
      a6 += ldnt4(src + (size_t)i6 * D_ + lane * 4);
      a7 += ldnt4(src + (size_t)i7 * D_ + lane * 4);
    }
    for (; k < n; k++) {
      int i0 = __shfl(idx, k, 64);
      a0 += ldnt4(src + (size_t)i0 * D_ + lane * 4);
    }
  }
  *accs = ((a0 + a1) + (a2 + a3)) + ((a4 + a5) + (a6 + a7));
}

// ---- fuseB: roles Bresenham-interleaved; segmean NT so gemm's E stays in L2 ----
__global__ __launch_bounds__(256) void k_fuseB(
    const u16* __restrict__ E,
    const float* __restrict__ fg, const float* __restrict__ fm,
    const int* __restrict__ cntg, const int* __restrict__ cnts,
    const int* __restrict__ listg, const int* __restrict__ lists,
    const int* __restrict__ nb, const int* __restrict__ plist,
    float* __restrict__ S, float* __restrict__ T, int* __restrict__ C,
    float* __restrict__ scal) {
  __shared__ __align__(16) u16 As[128 * 64];
  __shared__ __align__(16) u16 Bs[128 * 64];
  int blk = blockIdx.x;
  int tid = threadIdx.x, lane = tid & 63, wid = tid >> 6;

  int64_t p = (int64_t)blk * NS_;
  int srem = (int)(p % NTOT_);
  if (srem < NS_) {               // ---- segmean ----
    int sid = (int)(p / NTOT_);
    int b = sid * 4 + wid;
    int cg = cntg[b], cs = cnts[b];
    f32x4 sg, ss;
    wave_row_sum(fg, listg, b * CAPG, min(cg, CAPG), lane, &sg);
    wave_row_sum(fm, lists, b * CAPS, min(cs, CAPS), lane, &ss);
    float ig = 1.f / fmaxf((float)cg, 1.f);
    float is = 1.f / fmaxf((float)cs, 1.f);
    float dx = sg.x * ig - ss.x * is, dy = sg.y * ig - ss.y * is;
    float dz = sg.z * ig - ss.z * is, dw = sg.w * ig - ss.w * is;
    float v = wave_sum(dx * dx + dy * dy + dz * dz + dw * dw);
    __shared__ float r2[4];
    if (lane == 0) r2[wid] = (cg > 0 && cs > 0) ? sqrtf(v) : 0.f;
    __syncthreads();
    if (tid == 0) {
      float s = r2[0] + r2[1] + r2[2] + r2[3];
      if (s != 0.f) atomicAdd(&scal[0], s);
    }
    return;
  }

  int r = blk - (int)((p + NTOT_ - 1) / NTOT_);   // rank among non-S
  int64_t q = (int64_t)r * NG_;
  int grem = (int)(q % NR_);

  if (grem >= NG_) {              // ---- tfix (8 rows/wave) ----
    int tix = r - (int)((q + NR_ - 1) / NR_);
#pragma unroll
    for (int k8 = 0; k8 < 8; k8++) {
      int i = tix * 32 + wid * 8 + k8;
      int a = i & (B_ - 1);
      int n = min(nb[a], 32);
      u16x4 vi = *(const u16x4*)(E + (size_t)i * D_ + lane * 4);
      float ex = bf2f(vi.x), ey = bf2f(vi.y), ez = bf2f(vi.z), ew = bf2f(vi.w);
      float acc = -(ex * ex + ey * ey + ez * ez + ew * ew);
      for (int k = 0; k < n; k++) {
        int b = plist[a * 32 + k];
        u16x4 v1 = *(const u16x4*)(E + (size_t)b * D_ + lane * 4);
        u16x4 v2 = *(const u16x4*)(E + (size_t)(b + B_) * D_ + lane * 4);
        acc += ex * bf2f(v1.x) + ey * bf2f(v1.y) + ez * bf2f(v1.z) + ew * bf2f(v1.w);
        acc += ex * bf2f(v2.x) + ey * bf2f(v2.y) + ez * bf2f(v2.z) + ew * bf2f(v2.w);
      }
      acc = wave_sum(acc);
      if (lane == 0) { T[i] = 10.0f * acc; C[i] = 2 * n - 1; }
    }
    return;
  }

  // ---- gemm ----
  int t = (int)(q / NR_);
  int bi = (int)((129.0f - sqrtf(129.0f * 129.0f - 8.0f * (float)t)) * 0.5f);
  while ((bi + 1) * (129 - (bi + 1)) / 2 <= t) bi++;
  while (bi * (129 - bi) / 2 > t) bi--;
  int bj = bi + (t - bi * (129 - bi) / 2);

  int row0 = bi * 128, col0 = bj * 128;
  int wr = wid >> 1, wc = wid & 1;

  int rsub = lane >> 3;
  int csw  = (((lane & 7) ^ rsub) << 4) >> 1;

  f32x4 acc[4][4];
#pragma unroll
  for (int mi = 0; mi < 4; mi++)
#pragma unroll
    for (int ni = 0; ni < 4; ni++) {
      f32x4 z = {0.f, 0.f, 0.f, 0.f};
      acc[mi][ni] = z;
    }

  for (int kc = 0; kc < 4; ++kc) {
    __syncthreads();
#pragma unroll
    for (int it = 0; it < 4; it++) {
      int s = wid * 4 + it;
      int rr = s * 8 + rsub;
      gload16(E + (size_t)(row0 + rr) * D_ + kc * 64 + csw, As + s * 512);
      gload16(E + (size_t)(col0 + rr) * D_ + kc * 64 + csw, Bs + s * 512);
    }
    __syncthreads();
#pragma unroll
    for (int kk = 0; kk < 2; ++kk) {
      s16x8 af[4], bfr[4];
#pragma unroll
      for (int mi = 0; mi < 4; mi++) {
        int rA = wr * 64 + mi * 16 + (lane & 15);
        int cbf = kk * 64 + (lane >> 4) * 16;
        int addr = rA * 128 + (cbf ^ ((rA & 7) << 4));
        af[mi] = *(const s16x8*)((const char*)As + addr);
      }
#pragma unroll
      for (int ni = 0; ni < 4; ni++) {
        int rB = wc * 64 + ni * 16 + (lane & 15);
        int cbf = kk * 64 + (lane >> 4) * 16;
        int addr = rB * 128 + (cbf ^ ((rB & 7) << 4));
        bfr[ni] = *(const s16x8*)((const char*)Bs + addr);
      }
#pragma unroll
      for (int mi = 0; mi < 4; mi++)
#pragma unroll
        for (int ni = 0; ni < 4; ni++)
          acc[mi][ni] = __builtin_amdgcn_mfma_f32_16x16x32_bf16(af[mi], bfr[ni], acc[mi][ni], 0, 0, 0);
    }
  }

  int g = lane >> 4, cl = lane & 15;
  float colsum[4] = {0.f, 0.f, 0.f, 0.f};
#pragma unroll
  for (int mi = 0; mi < 4; mi++) {
#pragma unroll
    for (int reg = 0; reg < 4; ++reg) {
      int gi = row0 + wr * 64 + mi * 16 + g * 4 + reg;
      float vs = 0.f;
#pragma unroll
      for (int ni = 0; ni < 4; ni++) {
        float e = exp2f(acc[mi][ni][reg] * K2E - K2E);
        vs += e;
        colsum[ni] += e;
      }
#pragma unroll
      for (int m = 1; m < 16; m <<= 1) vs += __shfl_xor(vs, m, 64);
      if (cl == 0) atomicAdd(&S[gi], vs);
    }
  }
  if (bi != bj) {
#pragma unroll
    for (int ni = 0; ni < 4; ni++) {
      float cs = colsum[ni];
      cs += __shfl_xor(cs, 16, 64);
      cs += __shfl_xor(cs, 32, 64);
      if (g == 0) atomicAdd(&S[col0 + wc * 64 + ni * 16 + cl], cs);
    }
  }
}

// ---- final combine (+ l_prop fused) ----
__global__ void k_final(const float* __restrict__ S, const float* __restrict__ T,
                        const int* __restrict__ C, const float* __restrict__ scal,
                        const float* __restrict__ pp, const float* __restrict__ pt,
                        float* __restrict__ out) {
  float sp = 0.f;
  for (int i = threadIdx.x; i < B_ * 4; i += 256) {
    float d = pp[i] - pt[i];
    sp += d * d;
  }
  float rls = 0.f; int nv = 0;
  for (int i = threadIdx.x; i < N2_; i += 256) {
    int ci = C[i];
    if (ci > 0) { rls += (10.0f + logf(S[i])) - T[i] / (float)ci; nv++; }
  }
  rls = wave_sum(rls);
  sp  = wave_sum(sp);
  nv  = wave_sum_i(nv);
  __shared__ float r1[4], r3[4]; __shared__ int r2[4];
  int lane = threadIdx.x & 63, w = threadIdx.x >> 6;
  if (lane == 0) { r1[w] = rls; r2[w] = nv; r3[w] = sp; }
  __syncthreads();
  if (threadIdx.x == 0) {
    float rtot = r1[0] + r1[1] + r1[2] + r1[3];
    int nvt = r2[0] + r2[1] + r2[2] + r2[3];
    float sptot = r3[0] + r3[1] + r3[2] + r3[3];
    float l_contr = nvt > 0 ? rtot / (float)nvt : 0.f;
    int bmax = ((const int*)scal)[3];
    float bs = (float)bmax + 1.0f;
    float l_local_g = scal[0] / bs;
    float l_sc = scal[1] / (float)NM_;
    float l_prop = sptot / (float)(B_ * 4);
    float l_hes = 1.0f * l_local_g + 0.8f * l_contr + 1.0f * l_sc + 0.8f * l_contr + 0.5f * l_prop;
    out[0] = l_hes; out[1] = l_local_g; out[2] = l_contr;
    out[3] = l_sc;  out[4] = l_contr;   out[5] = l_prop;
  }
}

extern "C" void kernel_launch(void* const* d_in, const int* in_sizes, int n_in,
                              void* d_out, int out_size, void* d_ws, size_t ws_size,
                              hipStream_t stream) {
  if (ws_size < WS_NEED) return;
  const float* gm  = (const float*)d_in[0];
  const float* fg  = (const float*)d_in[1];
  const float* scm = (const float*)d_in[2];
  const float* scs = (const float*)d_in[3];
  const float* mot = (const float*)d_in[4];
  const float* shp = (const float*)d_in[5];
  const float* pp  = (const float*)d_in[6];
  const float* pt  = (const float*)d_in[7];
  const int* bg = (const int*)d_in[8];
  const int* bs = (const int*)d_in[9];
  float* out = (float*)d_out;
  char* ws = (char*)d_ws;

  int* cntg  = (int*)(ws + OFF_CNT_G);
  int* cnts  = (int*)(ws + OFF_CNT_S);
  int* nb    = (int*)(ws + OFF_NB);
  float* scal = (float*)(ws + OFF_SCAL);
  float* S   = (float*)(ws + OFF_S);
  float* T   = (float*)(ws + OFF_T);
  int* C     = (int*)(ws + OFF_C);
  int* plist = (int*)(ws + OFF_PLIST);
  int* listg = (int*)(ws + OFF_LIST_G);
  int* lists = (int*)(ws + OFF_LIST_S);
  u16* E     = (u16*)(ws + OFF_E);

  k_zero<<<24, 256, 0, stream>>>((u32x4*)ws);
  k_fuseA<<<8704, 256, 0, stream>>>(bg, bs, cntg, cnts, (int*)scal + 3,
                                    listg, lists, gm, scm, scs, shp, pp,
                                    E, nb, plist, scal);
  k_fuseB<<<NTOT_, 256, 0, stream>>>(E, fg, mot, cntg, cnts, listg, lists,
                                     nb, plist, S, T, C, scal);
  k_final<<<1, 256, 0, stream>>>(S, T, C, scal, pp, pt, out);
}